// Round 10
// baseline (530.944 us; speedup 1.0000x reference)
//
#include <hip/hip_runtime.h>
#include <cmath>

// Shapes
// B=128, S=4096, W_NUM=10000, CONT=FEAT=LSTM=256, AH=CH=128
// out = [logits 128*10000 | value 128 | h 128*256 | c 128*256]

#define B_ 128
#define S_ 4096
#define WN 10000
#define CD 256

// ---------------------------------------------------------------------------
// K1: x_cont partial GEMM.  part[ks][128,256-slice] = x[128,k-chunk] @ W^T.
// grid (16 n-tiles of 16, 40 k-chunks of 256), block 256.
// ---------------------------------------------------------------------------
__global__ __launch_bounds__(256) void k1_xcont(
    const float* __restrict__ x, const float* __restrict__ Wx,
    float* __restrict__ part) {
  const int nt = blockIdx.x;   // 0..15
  const int ks = blockIdx.y;   // 0..39
  const int t = threadIdx.x;
  __shared__ float4 xs[128][16];    // 128 rows x 64 k, XOR-swizzled
  __shared__ float4 wsW[16][16];
  const int o0 = nt * 16;
  const int og = t & 3;             // 4 output-groups of 4
  const int bg = t >> 2;            // 0..63 -> rows bg, bg+64
  const int bgx = bg & 7;
  float acc[2][4] = {{0.f, 0.f, 0.f, 0.f}, {0.f, 0.f, 0.f, 0.f}};
  for (int sub = 0; sub < 4; ++sub) {
    const int k0 = ks * 256 + sub * 64;
    for (int q = t; q < 2048; q += 256) {          // 128 x 16 f4
      const int row = q >> 4, c4 = q & 15;
      const int k = k0 + c4 * 4;
      float4 v = make_float4(0.f, 0.f, 0.f, 0.f);
      if (k < WN) v = *(const float4*)(x + (size_t)row * WN + k);
      xs[row][c4 ^ (row & 7)] = v;
    }
    {                                              // 16 x 16 f4, 1/thread
      const int row = t >> 4, c4 = t & 15;
      const int k = k0 + c4 * 4;
      float4 v = make_float4(0.f, 0.f, 0.f, 0.f);
      if (k < WN) v = *(const float4*)(Wx + (size_t)(o0 + row) * WN + k);
      wsW[row][c4 ^ (row & 7)] = v;
    }
    __syncthreads();
#pragma unroll
    for (int c4 = 0; c4 < 16; ++c4) {
      float4 wv[4];
#pragma unroll
      for (int i = 0; i < 4; ++i) wv[i] = wsW[og * 4 + i][c4 ^ ((og * 4 + i) & 7)];
#pragma unroll
      for (int j = 0; j < 2; ++j) {
        const float4 xv = xs[bg + j * 64][c4 ^ bgx];
#pragma unroll
        for (int i = 0; i < 4; ++i)
          acc[j][i] += xv.x * wv[i].x + xv.y * wv[i].y + xv.z * wv[i].z + xv.w * wv[i].w;
      }
    }
    __syncthreads();
  }
#pragma unroll
  for (int j = 0; j < 2; ++j) {
    const int bb = bg + j * 64;
#pragma unroll
    for (int i = 0; i < 4; ++i)
      part[(size_t)ks * 32768 + bb * 256 + o0 + og * 4 + i] = acc[j][i];
  }
}

// ---------------------------------------------------------------------------
// K2: reduce partials -> x_cont; controller: control, key_v, strength, key_n.
// grid 128 (batch), block 256 (output dim).
// ---------------------------------------------------------------------------
__global__ __launch_bounds__(256) void k2_controller(
    const float* __restrict__ part, const float* __restrict__ bx,
    const float* __restrict__ h_tm1, const float* __restrict__ Wh,
    const float* __restrict__ bh, const float* __restrict__ Wk,
    const float* __restrict__ bk, const float* __restrict__ Ws,
    const float* __restrict__ bs, float* __restrict__ x_cont,
    float* __restrict__ key_v, float* __restrict__ strength,
    float* __restrict__ key_n) {
  const int b = blockIdx.x, t = threadIdx.x;
  __shared__ float hs[256], cs[256];
  __shared__ float r1[4], r2[4];
  hs[t] = h_tm1[b * 256 + t];
  float xc = bx[t];
  for (int ks = 0; ks < 40; ++ks) xc += part[(size_t)ks * 32768 + b * 256 + t];
  x_cont[b * 256 + t] = xc;
  __syncthreads();
  float hc = bh[t];
  {
    const float* w = Wh + (size_t)t * 256;
    for (int k = 0; k < 256; k += 4) {
      float4 wv = *(const float4*)(w + k);
      hc += hs[k] * wv.x + hs[k + 1] * wv.y + hs[k + 2] * wv.z + hs[k + 3] * wv.w;
    }
  }
  const float ctl = fmaxf(xc + hc, 0.f);
  cs[t] = ctl;
  __syncthreads();
  float kvv = bk[t];
  {
    const float* w = Wk + (size_t)t * 256;
    for (int k = 0; k < 256; k += 4) {
      float4 wv = *(const float4*)(w + k);
      kvv += cs[k] * wv.x + cs[k + 1] * wv.y + cs[k + 2] * wv.z + cs[k + 3] * wv.w;
    }
  }
  kvv = tanhf(kvv);
  key_v[b * 256 + t] = kvv;
  float v1 = kvv * kvv;
  float v2 = ctl * Ws[t];
  for (int off = 32; off; off >>= 1) {
    v1 += __shfl_xor(v1, off);
    v2 += __shfl_xor(v2, off);
  }
  const int w_ = t >> 6, lane = t & 63;
  if (lane == 0) { r1[w_] = v1; r2[w_] = v2; }
  __syncthreads();
  if (t == 0) {
    const float n2 = r1[0] + r1[1] + r1[2] + r1[3];
    const float sd = r2[0] + r2[1] + r2[2] + r2[3];
    key_n[b] = sqrtf(n2);
    strength[b] = fmaxf(sd + bs[0], 0.f) + 1.f;
  }
}

// ---------------------------------------------------------------------------
// DPP 16-lane butterfly sum via row_ror (pure VALU, no DS pipe).
// ---------------------------------------------------------------------------
__device__ __forceinline__ float dpp_add16(float x) {
  int t;
  t = __builtin_amdgcn_update_dpp(0, __float_as_int(x), 0x121, 0xf, 0xf, true);
  x += __int_as_float(t);   // ror:1
  t = __builtin_amdgcn_update_dpp(0, __float_as_int(x), 0x122, 0xf, 0xf, true);
  x += __int_as_float(t);   // ror:2
  t = __builtin_amdgcn_update_dpp(0, __float_as_int(x), 0x124, 0xf, 0xf, true);
  x += __int_as_float(t);   // ror:4
  t = __builtin_amdgcn_update_dpp(0, __float_as_int(x), 0x128, 0xf, 0xf, true);
  x += __int_as_float(t);   // ror:8
  return x;
}

// ---------------------------------------------------------------------------
// K3: content attention (R9 structure: DMA-staged ring, counted vmcnt, DPP).
// *** DIAGNOSTIC ROUND: rep=0..3 IDEMPOTENT repeats — o/lsum reset per rep,
// identical recompute, epilogue uses last rep => bitwise-identical outputs.
// Purpose: surface K3 above the ~317us harness fills with real counters, and
// get exact non-K3 = total_dur - K3_dispatch_dur.  Five K3 interventions
// (R5-R9) produced +11us against an INFERRED K3~139us; measure before more. ***
// grid (4 s-splits, 128 batch), block 256 = 4 waves; 16-lane group per slot.
// ---------------------------------------------------------------------------
__global__ __launch_bounds__(256) void k3_attn(
    const float* __restrict__ feat, const float* __restrict__ key_v,
    const float* __restrict__ strength, const float* __restrict__ key_n,
    float* __restrict__ att_part) {
  const int ss = blockIdx.x;   // 0..3
  const int b = blockIdx.y;    // 0..127
  const int t = threadIdx.x;
  const int w = t >> 6, lane = t & 63;
  const int g = lane >> 4;     // group (slot within wave-quad)
  const int l = lane & 15;     // lane in group

  __shared__ __align__(16) float tile[4][16][256];   // 64 KB, 4-deep ring
  __shared__ float wo[4][256];
  __shared__ float wl[4];

  const float str = strength[b];
  const float kn = key_n[b];
  float4 kf[4];
#pragma unroll
  for (int p = 0; p < 4; ++p)
    kf[p] = *(const float4*)(key_v + b * 256 + p * 64 + l * 4);

  const float* fbase = feat + ((size_t)b * S_ + (size_t)ss * 1024) * 256;

#define STAGE(nt, buf)                                                        \
  {                                                                           \
    _Pragma("unroll") for (int j = 0; j < 4; ++j) {                           \
      const int row_ = w * 4 + j;                                             \
      const float* gp_ = fbase + ((size_t)(nt)*16 + row_) * 256 + lane * 4;   \
      __builtin_amdgcn_global_load_lds(                                       \
          (const __attribute__((address_space(1))) void*)gp_,                 \
          (__attribute__((address_space(3))) void*)&tile[buf][row_][0], 16,   \
          0, 0);                                                              \
    }                                                                         \
  }

  float4 o[4];
  float lsum;

#define COMPUTE(buf)                                                          \
  {                                                                           \
    const int row_ = w * 4 + g;                                               \
    const float* rp_ = &tile[buf][row_][l * 4];                               \
    const float4 f0 = *(const float4*)(rp_);                                  \
    const float4 f1 = *(const float4*)(rp_ + 64);                             \
    const float4 f2 = *(const float4*)(rp_ + 128);                            \
    const float4 f3 = *(const float4*)(rp_ + 192);                            \
    float dp0 = f0.x * kf[0].x + f0.y * kf[0].y + f0.z * kf[0].z + f0.w * kf[0].w; \
    float dp1 = f1.x * kf[1].x + f1.y * kf[1].y + f1.z * kf[1].z + f1.w * kf[1].w; \
    float dp2 = f2.x * kf[2].x + f2.y * kf[2].y + f2.z * kf[2].z + f2.w * kf[2].w; \
    float dp3 = f3.x * kf[3].x + f3.y * kf[3].y + f3.z * kf[3].z + f3.w * kf[3].w; \
    float nn0 = f0.x * f0.x + f0.y * f0.y + f0.z * f0.z + f0.w * f0.w;        \
    float nn1 = f1.x * f1.x + f1.y * f1.y + f1.z * f1.z + f1.w * f1.w;        \
    float nn2 = f2.x * f2.x + f2.y * f2.y + f2.z * f2.z + f2.w * f2.w;        \
    float nn3 = f3.x * f3.x + f3.y * f3.y + f3.z * f3.z + f3.w * f3.w;        \
    float d_ = (dp0 + dp1) + (dp2 + dp3);                                     \
    float n2_ = (nn0 + nn1) + (nn2 + nn3);                                    \
    d_ = dpp_add16(d_);                                                       \
    n2_ = dpp_add16(n2_);                                                     \
    const float sc_ = str * d_ / (sqrtf(n2_) * kn + 1e-8f);                   \
    const float a_ = __expf(sc_ - str);                                       \
    lsum += a_;                                                               \
    o[0].x += a_ * f0.x; o[0].y += a_ * f0.y; o[0].z += a_ * f0.z; o[0].w += a_ * f0.w; \
    o[1].x += a_ * f1.x; o[1].y += a_ * f1.y; o[1].z += a_ * f1.z; o[1].w += a_ * f1.w; \
    o[2].x += a_ * f2.x; o[2].y += a_ * f2.y; o[2].z += a_ * f2.z; o[2].w += a_ * f2.w; \
    o[3].x += a_ * f3.x; o[3].y += a_ * f3.y; o[3].z += a_ * f3.z; o[3].w += a_ * f3.w; \
  }

#pragma unroll 1
  for (int rep = 0; rep < 4; ++rep) {
    lsum = 0.f;
#pragma unroll
    for (int p = 0; p < 4; ++p) o[p] = make_float4(0.f, 0.f, 0.f, 0.f);
    // prologue: 3 tiles in flight (12 DMAs/wave); vmcnt==0 at rep entry
    STAGE(0, 0);
    STAGE(1, 1);
    STAGE(2, 2);
#pragma unroll 1
    for (int nt = 0; nt < 61; ++nt) {
      asm volatile("s_waitcnt vmcnt(8)" ::: "memory");  // oldest tile resident
      STAGE(nt + 3, (nt + 3) & 3);                      // issue-early refill
      COMPUTE(nt & 3);
    }
    asm volatile("s_waitcnt vmcnt(8)" ::: "memory");
    COMPUTE(1);   // tile 61
    asm volatile("s_waitcnt vmcnt(4)" ::: "memory");
    COMPUTE(2);   // tile 62
    asm volatile("s_waitcnt vmcnt(0)" ::: "memory");
    COMPUTE(3);   // tile 63
  }
#undef STAGE
#undef COMPUTE

  // cross-group combine (groups hold disjoint slots, same d-fragments)
#pragma unroll
  for (int off = 16; off <= 32; off <<= 1) {
    lsum += __shfl_xor(lsum, off);
#pragma unroll
    for (int p = 0; p < 4; ++p) {
      o[p].x += __shfl_xor(o[p].x, off);
      o[p].y += __shfl_xor(o[p].y, off);
      o[p].z += __shfl_xor(o[p].z, off);
      o[p].w += __shfl_xor(o[p].w, off);
    }
  }
  if (g == 0) {
#pragma unroll
    for (int p = 0; p < 4; ++p) *(float4*)&wo[w][p * 64 + l * 4] = o[p];
    if (l == 0) wl[w] = lsum;
  }
  __syncthreads();
  const float od = wo[0][t] + wo[1][t] + wo[2][t] + wo[3][t];
  float* apo = att_part + (size_t)(b * 4 + ss) * 264;
  if (t == 0) apo[0] = wl[0] + wl[1] + wl[2] + wl[3];
  apo[4 + t] = od;
}

// ---------------------------------------------------------------------------
// K4a: combine split partials (plain sums) -> cand_att_vec; attention gate;
// build inp_cat[b][768] = [att_vec | x_cont | h_tm1].  grid 128, block 256.
// ---------------------------------------------------------------------------
__global__ __launch_bounds__(256) void k4a_gate(
    const float* __restrict__ att_part, const float* __restrict__ h_tm1,
    const float* __restrict__ x_cont, const float* __restrict__ Wg,
    const float* __restrict__ bg_, float* __restrict__ inp_cat) {
  const int b = blockIdx.x, t = threadIdx.x;
  const float* ap = att_part + (size_t)b * 4 * 264;
  float lg = 0.f, od = 0.f;
#pragma unroll
  for (int ss = 0; ss < 4; ++ss) {
    lg += ap[ss * 264];
    od += ap[ss * 264 + 4 + t];
  }
  const float cand = od / lg;
  const float hv = h_tm1[b * 256 + t];
  const float xc = x_cont[b * 256 + t];
  float v = cand * Wg[t] + hv * Wg[256 + t] + xc * Wg[512 + t];
  for (int off = 32; off; off >>= 1) v += __shfl_xor(v, off);
  __shared__ float rr[4];
  __shared__ float gsh;
  const int w_ = t >> 6, lane = t & 63;
  if (lane == 0) rr[w_] = v;
  __syncthreads();
  if (t == 0) {
    const float s = rr[0] + rr[1] + rr[2] + rr[3] + bg_[0];
    gsh = 1.f / (1.f + expf(-s));
  }
  __syncthreads();
  inp_cat[b * 768 + t] = cand * gsh;
  inp_cat[b * 768 + 256 + t] = xc;
  inp_cat[b * 768 + 512 + t] = hv;
}

// ---------------------------------------------------------------------------
// K4b: LSTM cell.  Block bj handles columns {j0, j0+1} x all 4 gates x 128 b,
// K = 768 ([att_vec,x_cont] via W_ih then h_tm1 via W_hh).  Fuses c/h update.
// grid 128, block 256.
// ---------------------------------------------------------------------------
__global__ __launch_bounds__(256) void k4b_lstm(
    const float* __restrict__ inp_cat, const float* __restrict__ Wih,
    const float* __restrict__ bih, const float* __restrict__ Whh,
    const float* __restrict__ bhh, const float* __restrict__ c_tm1,
    float* __restrict__ h_out, float* __restrict__ c_out) {
  const int j0 = blockIdx.x * 2;
  const int t = threadIdx.x;
  __shared__ float inp_s[128][132];
  __shared__ float w_s[8][132];
  const int b = t >> 1, half = t & 1;
  float acc[4] = {0.f, 0.f, 0.f, 0.f};
  for (int kc = 0; kc < 6; ++kc) {
    const int kbase = kc * 128;
    for (int q = t; q < 4096; q += 256) {     // 128 x 128 floats
      const int row = q >> 5, c4 = q & 31;
      *(float4*)&inp_s[row][c4 * 4] =
          *(const float4*)(inp_cat + (size_t)row * 768 + kbase + c4 * 4);
    }
    {                                          // 8 x 128 floats, one f4/thread
      const int row = t >> 5, c4 = t & 31;
      const int gate = row & 3;
      const int j = j0 + (row >> 2);
      const int og = gate * 256 + j;
      const int kg = kbase + c4 * 4;
      float4 v;
      if (kg < 512) v = *(const float4*)(Wih + (size_t)og * 512 + kg);
      else          v = *(const float4*)(Whh + (size_t)og * 256 + (kg - 512));
      *(float4*)&w_s[row][c4 * 4] = v;
    }
    __syncthreads();
    for (int k = 0; k < 128; k += 4) {
      const float4 iv = *(const float4*)&inp_s[b][k];
#pragma unroll
      for (int g = 0; g < 4; ++g) {
        const float4 wv = *(const float4*)&w_s[half * 4 + g][k];
        acc[g] += iv.x * wv.x + iv.y * wv.y + iv.z * wv.z + iv.w * wv.w;
      }
    }
    __syncthreads();
  }
  const int j = j0 + half;
  const float gi = acc[0] + bih[j] + bhh[j];
  const float gf = acc[1] + bih[256 + j] + bhh[256 + j];
  const float gg = acc[2] + bih[512 + j] + bhh[512 + j];
  const float go = acc[3] + bih[768 + j] + bhh[768 + j];
  const float ct = c_tm1[b * 256 + j];
  const float i_ = 1.f / (1.f + expf(-gi));
  const float f_ = 1.f / (1.f + expf(-gf));
  const float g_ = tanhf(gg);
  const float o_ = 1.f / (1.f + expf(-go));
  const float c = f_ * ct + i_ * g_;
  const float h = o_ * tanhf(c);
  h_out[b * 256 + j] = h;
  c_out[b * 256 + j] = c;
}

// ---------------------------------------------------------------------------
// K5: head hidden layers (post-relu).  grid 128 (batch), block 256
// (t<128 -> actor_hid, t>=128 -> critic_hid).
// ---------------------------------------------------------------------------
__global__ __launch_bounds__(256) void k5_hid(
    const float* __restrict__ h_in, const float* __restrict__ Wah,
    const float* __restrict__ bah, const float* __restrict__ Wch,
    const float* __restrict__ bch, float* __restrict__ hidA,
    float* __restrict__ hidC) {
  const int b = blockIdx.x, t = threadIdx.x;
  __shared__ float hs[256];
  hs[t] = h_in[b * 256 + t];
  __syncthreads();
  const float* W = (t < 128) ? (Wah + (size_t)t * 256) : (Wch + (size_t)(t - 128) * 256);
  float s = (t < 128) ? bah[t] : bch[t - 128];
  for (int k = 0; k < 256; k += 4) {
    const float4 w = *(const float4*)(W + k);
    s += hs[k] * w.x + hs[k + 1] * w.y + hs[k + 2] * w.z + hs[k + 3] * w.w;
  }
  s = fmaxf(s, 0.f);
  if (t < 128) hidA[b * 128 + t] = s;
  else         hidC[b * 128 + (t - 128)] = s;
}

// ---------------------------------------------------------------------------
// K6: action logits GEMM [128,10000] = hidA[128,128] @ W_actor^T + b.
// grid (158, 4): batch split 4x; (157,0) computes value.  XOR-swizzled LDS.
// ---------------------------------------------------------------------------
__global__ __launch_bounds__(256) void k6_heads(
    const float* __restrict__ hidA, const float* __restrict__ hidC,
    const float* __restrict__ Wa, const float* __restrict__ ba,
    const float* __restrict__ Wc, const float* __restrict__ bc,
    float* __restrict__ logits, float* __restrict__ value) {
  const int t = threadIdx.x;
  const int bx = blockIdx.x, by = blockIdx.y;
  if (bx == 157) {
    if (by == 0 && t < 128) {
      const float* hc = hidC + (size_t)t * 128;
      float s = bc[0];
      for (int k = 0; k < 128; k += 4) {
        const float4 w = *(const float4*)(Wc + k);
        s += hc[k] * w.x + hc[k + 1] * w.y + hc[k + 2] * w.z + hc[k + 3] * w.w;
      }
      value[t] = s;
    }
    return;
  }
  const int o0 = bx * 64;
  const int b0 = by * 32;
  __shared__ float4 ha[32][32];
  __shared__ float4 wa[64][32];
  for (int q = t; q < 1024; q += 256) {    // 32 rows x 32 f4
    const int row = q >> 5, c4 = q & 31;
    ha[row][c4 ^ ((row >> 2) & 7)] =
        *(const float4*)(hidA + (size_t)(b0 + row) * 128 + c4 * 4);
  }
  for (int q = t; q < 2048; q += 256) {    // 64 rows x 32 f4
    const int row = q >> 5, c4 = q & 31;
    const int o = o0 + row;
    float4 v = make_float4(0.f, 0.f, 0.f, 0.f);
    if (o < WN) v = *(const float4*)(Wa + (size_t)o * 128 + c4 * 4);
    wa[row][c4 ^ ((row >> 2) & 7)] = v;
  }
  __syncthreads();
  const int og = t & 15, bq = t >> 4;      // 16 out-groups x 16 batch-groups
  float acc[2][4];
#pragma unroll
  for (int r = 0; r < 2; ++r)
#pragma unroll
    for (int i = 0; i < 4; ++i) acc[r][i] = 0.f;
#pragma unroll 4
  for (int c4 = 0; c4 < 32; ++c4) {
    float4 wv[4];
#pragma unroll
    for (int i = 0; i < 4; ++i) wv[i] = wa[og * 4 + i][c4 ^ (og & 7)];
#pragma unroll
    for (int r = 0; r < 2; ++r) {
      const int row = bq * 2 + r;
      const float4 hv = ha[row][c4 ^ ((row >> 2) & 7)];
#pragma unroll
      for (int i = 0; i < 4; ++i)
        acc[r][i] += hv.x * wv[i].x + hv.y * wv[i].y + hv.z * wv[i].z + hv.w * wv[i].w;
    }
  }
  const int obase = o0 + og * 4;
#pragma unroll
  for (int r = 0; r < 2; ++r) {
    const int bb = b0 + bq * 2 + r;
    if (obase + 3 < WN) {
      const float4 bias = *(const float4*)(ba + obase);
      float4 res;
      res.x = acc[r][0] + bias.x;
      res.y = acc[r][1] + bias.y;
      res.z = acc[r][2] + bias.z;
      res.w = acc[r][3] + bias.w;
      *(float4*)(logits + (size_t)bb * WN + obase) = res;
    } else {
      for (int i = 0; i < 4; ++i)
        if (obase + i < WN) logits[(size_t)bb * WN + obase + i] = acc[r][i] + ba[obase + i];
    }
  }
}

// ---------------------------------------------------------------------------
extern "C" void kernel_launch(void* const* d_in, const int* in_sizes, int n_in,
                              void* d_out, int out_size, void* d_ws, size_t ws_size,
                              hipStream_t stream) {
  const float* x     = (const float*)d_in[0];
  const float* feat  = (const float*)d_in[1];
  const float* h_tm1 = (const float*)d_in[2];
  const float* c_tm1 = (const float*)d_in[3];
  const float* Wx2c  = (const float*)d_in[4];
  const float* bx2c  = (const float*)d_in[5];
  const float* Wh2c  = (const float*)d_in[6];
  const float* bh2c  = (const float*)d_in[7];
  const float* Wc2k  = (const float*)d_in[8];
  const float* bc2k  = (const float*)d_in[9];
  const float* Wc2s  = (const float*)d_in[10];
  const float* bc2s  = (const float*)d_in[11];
  const float* Wag   = (const float*)d_in[12];
  const float* bag   = (const float*)d_in[13];
  const float* Wih   = (const float*)d_in[14];
  const float* bih   = (const float*)d_in[15];
  const float* Whh   = (const float*)d_in[16];
  const float* bhh   = (const float*)d_in[17];
  const float* Wah   = (const float*)d_in[18];
  const float* bah   = (const float*)d_in[19];
  const float* Wch   = (const float*)d_in[20];
  const float* bch   = (const float*)d_in[21];
  const float* Wa    = (const float*)d_in[22];
  const float* ba    = (const float*)d_in[23];
  const float* Wc    = (const float*)d_in[24];
  const float* bc    = (const float*)d_in[25];

  float* out    = (float*)d_out;
  float* logits = out;                 // 1,280,000
  float* value  = out + 1280000;       // 128
  float* h_out  = out + 1280128;       // 32,768
  float* c_out  = out + 1312896;       // 32,768

  float* wsf      = (float*)d_ws;
  float* part     = wsf;               // 40*32768 = 1,310,720
  float* x_cont   = part + 1310720;    // 32,768
  float* key_v    = x_cont + 32768;    // 32,768
  float* strength = key_v + 32768;     // 128
  float* key_n    = strength + 128;    // 128
  float* att_part = key_n + 128;       // 128*4*264 = 135,168
  float* inp_cat  = att_part + 135168; // 128*768 = 98,304
  float* hidA     = inp_cat + 98304;   // 16,384
  float* hidC     = hidA + 16384;      // 16,384

  k1_xcont<<<dim3(16, 40), 256, 0, stream>>>(x, Wx2c, part);
  k2_controller<<<128, 256, 0, stream>>>(part, bx2c, h_tm1, Wh2c, bh2c,
                                         Wc2k, bc2k, Wc2s, bc2s,
                                         x_cont, key_v, strength, key_n);
  k3_attn<<<dim3(4, 128), 256, 0, stream>>>(feat, key_v, strength, key_n, att_part);
  k4a_gate<<<128, 256, 0, stream>>>(att_part, h_tm1, x_cont, Wag, bag, inp_cat);
  k4b_lstm<<<128, 256, 0, stream>>>(inp_cat, Wih, bih, Whh, bhh, c_tm1, h_out, c_out);
  k5_hid<<<128, 256, 0, stream>>>(h_out, Wah, bah, Wch, bch, hidA, hidC);
  k6_heads<<<dim3(158, 4), 256, 0, stream>>>(hidA, hidC, Wa, ba, Wc, bc, logits, value);
}

// Round 11
// 275.829 us; speedup vs baseline: 1.9249x; 1.9249x over previous
//
#include <hip/hip_runtime.h>
#include <cmath>

// Shapes
// B=128, S=4096, W_NUM=10000, CONT=FEAT=LSTM=256, AH=CH=128
// out = [logits 128*10000 | value 128 | h 128*256 | c 128*256]

#define B_ 128
#define S_ 4096
#define WN 10000
#define CD 256

// ---------------------------------------------------------------------------
// K1: x_cont partial GEMM.  part[ks][128,256-slice] = x[128,k-chunk] @ W^T.
// grid (16 n-tiles of 16, 40 k-chunks of 256), block 256.
// ---------------------------------------------------------------------------
__global__ __launch_bounds__(256) void k1_xcont(
    const float* __restrict__ x, const float* __restrict__ Wx,
    float* __restrict__ part) {
  const int nt = blockIdx.x;   // 0..15
  const int ks = blockIdx.y;   // 0..39
  const int t = threadIdx.x;
  __shared__ float4 xs[128][16];    // 128 rows x 64 k, XOR-swizzled
  __shared__ float4 wsW[16][16];
  const int o0 = nt * 16;
  const int og = t & 3;             // 4 output-groups of 4
  const int bg = t >> 2;            // 0..63 -> rows bg, bg+64
  const int bgx = bg & 7;
  float acc[2][4] = {{0.f, 0.f, 0.f, 0.f}, {0.f, 0.f, 0.f, 0.f}};
  for (int sub = 0; sub < 4; ++sub) {
    const int k0 = ks * 256 + sub * 64;
    for (int q = t; q < 2048; q += 256) {          // 128 x 16 f4
      const int row = q >> 4, c4 = q & 15;
      const int k = k0 + c4 * 4;
      float4 v = make_float4(0.f, 0.f, 0.f, 0.f);
      if (k < WN) v = *(const float4*)(x + (size_t)row * WN + k);
      xs[row][c4 ^ (row & 7)] = v;
    }
    {                                              // 16 x 16 f4, 1/thread
      const int row = t >> 4, c4 = t & 15;
      const int k = k0 + c4 * 4;
      float4 v = make_float4(0.f, 0.f, 0.f, 0.f);
      if (k < WN) v = *(const float4*)(Wx + (size_t)(o0 + row) * WN + k);
      wsW[row][c4 ^ (row & 7)] = v;
    }
    __syncthreads();
#pragma unroll
    for (int c4 = 0; c4 < 16; ++c4) {
      float4 wv[4];
#pragma unroll
      for (int i = 0; i < 4; ++i) wv[i] = wsW[og * 4 + i][c4 ^ ((og * 4 + i) & 7)];
#pragma unroll
      for (int j = 0; j < 2; ++j) {
        const float4 xv = xs[bg + j * 64][c4 ^ bgx];
#pragma unroll
        for (int i = 0; i < 4; ++i)
          acc[j][i] += xv.x * wv[i].x + xv.y * wv[i].y + xv.z * wv[i].z + xv.w * wv[i].w;
      }
    }
    __syncthreads();
  }
#pragma unroll
  for (int j = 0; j < 2; ++j) {
    const int bb = bg + j * 64;
#pragma unroll
    for (int i = 0; i < 4; ++i)
      part[(size_t)ks * 32768 + bb * 256 + o0 + og * 4 + i] = acc[j][i];
  }
}

// ---------------------------------------------------------------------------
// K2: reduce partials -> x_cont; controller: control, key_v, strength, key_n.
// grid 128 (batch), block 256 (output dim).
// ---------------------------------------------------------------------------
__global__ __launch_bounds__(256) void k2_controller(
    const float* __restrict__ part, const float* __restrict__ bx,
    const float* __restrict__ h_tm1, const float* __restrict__ Wh,
    const float* __restrict__ bh, const float* __restrict__ Wk,
    const float* __restrict__ bk, const float* __restrict__ Ws,
    const float* __restrict__ bs, float* __restrict__ x_cont,
    float* __restrict__ key_v, float* __restrict__ strength,
    float* __restrict__ key_n) {
  const int b = blockIdx.x, t = threadIdx.x;
  __shared__ float hs[256], cs[256];
  __shared__ float r1[4], r2[4];
  hs[t] = h_tm1[b * 256 + t];
  float xc = bx[t];
  for (int ks = 0; ks < 40; ++ks) xc += part[(size_t)ks * 32768 + b * 256 + t];
  x_cont[b * 256 + t] = xc;
  __syncthreads();
  float hc = bh[t];
  {
    const float* w = Wh + (size_t)t * 256;
    for (int k = 0; k < 256; k += 4) {
      float4 wv = *(const float4*)(w + k);
      hc += hs[k] * wv.x + hs[k + 1] * wv.y + hs[k + 2] * wv.z + hs[k + 3] * wv.w;
    }
  }
  const float ctl = fmaxf(xc + hc, 0.f);
  cs[t] = ctl;
  __syncthreads();
  float kvv = bk[t];
  {
    const float* w = Wk + (size_t)t * 256;
    for (int k = 0; k < 256; k += 4) {
      float4 wv = *(const float4*)(w + k);
      kvv += cs[k] * wv.x + cs[k + 1] * wv.y + cs[k + 2] * wv.z + cs[k + 3] * wv.w;
    }
  }
  kvv = tanhf(kvv);
  key_v[b * 256 + t] = kvv;
  float v1 = kvv * kvv;
  float v2 = ctl * Ws[t];
  for (int off = 32; off; off >>= 1) {
    v1 += __shfl_xor(v1, off);
    v2 += __shfl_xor(v2, off);
  }
  const int w_ = t >> 6, lane = t & 63;
  if (lane == 0) { r1[w_] = v1; r2[w_] = v2; }
  __syncthreads();
  if (t == 0) {
    const float n2 = r1[0] + r1[1] + r1[2] + r1[3];
    const float sd = r2[0] + r2[1] + r2[2] + r2[3];
    key_n[b] = sqrtf(n2);
    strength[b] = fmaxf(sd + bs[0], 0.f) + 1.f;
  }
}

// ---------------------------------------------------------------------------
// DPP 16-lane butterfly sum via row_ror (pure VALU, no DS pipe).
// ---------------------------------------------------------------------------
__device__ __forceinline__ float dpp_add16(float x) {
  int t;
  t = __builtin_amdgcn_update_dpp(0, __float_as_int(x), 0x121, 0xf, 0xf, true);
  x += __int_as_float(t);   // ror:1
  t = __builtin_amdgcn_update_dpp(0, __float_as_int(x), 0x122, 0xf, 0xf, true);
  x += __int_as_float(t);   // ror:2
  t = __builtin_amdgcn_update_dpp(0, __float_as_int(x), 0x124, 0xf, 0xf, true);
  x += __int_as_float(t);   // ror:4
  t = __builtin_amdgcn_update_dpp(0, __float_as_int(x), 0x128, 0xf, 0xf, true);
  x += __int_as_float(t);   // ror:8
  return x;
}

// ---------------------------------------------------------------------------
// K3: content attention, fixed-shift softmax (score < str since |cos|<1).
// R10 diag: K3 cold = 155us @ 3.46 TB/s, Occupancy 22.5% (LDS 70KB -> 2
// blocks/CU); L3-warm reps hit 6.2 TB/s effective => pipeline fine, issue
// contexts too few.  THIS ROUND: ring 4->2 bufs (LDS 36.9KB -> 4 blocks/CU,
// 16 waves/CU, ~45% occ), grid 8 s-splits x 128 = 1024 blocks = 4/CU exact.
// Barrierless counted-vmcnt; STAGE after COMPUTE (depth-2 overwrites the
// just-consumed buf); wo kept separate (aliasing races without barriers).
// ---------------------------------------------------------------------------
__global__ __launch_bounds__(256) void k3_attn(
    const float* __restrict__ feat, const float* __restrict__ key_v,
    const float* __restrict__ strength, const float* __restrict__ key_n,
    float* __restrict__ att_part) {
  const int ss = blockIdx.x;   // 0..7
  const int b = blockIdx.y;    // 0..127
  const int t = threadIdx.x;
  const int w = t >> 6, lane = t & 63;
  const int g = lane >> 4;     // group (slot within wave-quad)
  const int l = lane & 15;     // lane in group

  __shared__ __align__(16) float tile[2][16][256];   // 32 KB double buffer
  __shared__ float wo[4][256];
  __shared__ float wl[4];

  const float str = strength[b];
  const float kn = key_n[b];
  float4 kf[4];
#pragma unroll
  for (int p = 0; p < 4; ++p)
    kf[p] = *(const float4*)(key_v + b * 256 + p * 64 + l * 4);

  const float* fbase = feat + ((size_t)b * S_ + (size_t)ss * 512) * 256;

  // wave w DMA-stages ITS OWN rows w*4..w*4+3 of tile nt (1 row = 1 instr)
#define STAGE(nt, buf)                                                        \
  {                                                                           \
    _Pragma("unroll") for (int j = 0; j < 4; ++j) {                           \
      const int row_ = w * 4 + j;                                             \
      const float* gp_ = fbase + ((size_t)(nt)*16 + row_) * 256 + lane * 4;   \
      __builtin_amdgcn_global_load_lds(                                       \
          (const __attribute__((address_space(1))) void*)gp_,                 \
          (__attribute__((address_space(3))) void*)&tile[buf][row_][0], 16,   \
          0, 0);                                                              \
    }                                                                         \
  }

  float4 o[4];
#pragma unroll
  for (int p = 0; p < 4; ++p) o[p] = make_float4(0.f, 0.f, 0.f, 0.f);
  float lsum = 0.f;

  // wave w consumes row w*4+g of the given ring buffer (its own staged rows)
#define COMPUTE(buf)                                                          \
  {                                                                           \
    const int row_ = w * 4 + g;                                               \
    const float* rp_ = &tile[buf][row_][l * 4];                               \
    const float4 f0 = *(const float4*)(rp_);                                  \
    const float4 f1 = *(const float4*)(rp_ + 64);                             \
    const float4 f2 = *(const float4*)(rp_ + 128);                            \
    const float4 f3 = *(const float4*)(rp_ + 192);                            \
    float dp0 = f0.x * kf[0].x + f0.y * kf[0].y + f0.z * kf[0].z + f0.w * kf[0].w; \
    float dp1 = f1.x * kf[1].x + f1.y * kf[1].y + f1.z * kf[1].z + f1.w * kf[1].w; \
    float dp2 = f2.x * kf[2].x + f2.y * kf[2].y + f2.z * kf[2].z + f2.w * kf[2].w; \
    float dp3 = f3.x * kf[3].x + f3.y * kf[3].y + f3.z * kf[3].z + f3.w * kf[3].w; \
    float nn0 = f0.x * f0.x + f0.y * f0.y + f0.z * f0.z + f0.w * f0.w;        \
    float nn1 = f1.x * f1.x + f1.y * f1.y + f1.z * f1.z + f1.w * f1.w;        \
    float nn2 = f2.x * f2.x + f2.y * f2.y + f2.z * f2.z + f2.w * f2.w;        \
    float nn3 = f3.x * f3.x + f3.y * f3.y + f3.z * f3.z + f3.w * f3.w;        \
    float d_ = (dp0 + dp1) + (dp2 + dp3);                                     \
    float n2_ = (nn0 + nn1) + (nn2 + nn3);                                    \
    d_ = dpp_add16(d_);                                                       \
    n2_ = dpp_add16(n2_);                                                     \
    const float sc_ = str * d_ / (sqrtf(n2_) * kn + 1e-8f);                   \
    const float a_ = __expf(sc_ - str);                                       \
    lsum += a_;                                                               \
    o[0].x += a_ * f0.x; o[0].y += a_ * f0.y; o[0].z += a_ * f0.z; o[0].w += a_ * f0.w; \
    o[1].x += a_ * f1.x; o[1].y += a_ * f1.y; o[1].z += a_ * f1.z; o[1].w += a_ * f1.w; \
    o[2].x += a_ * f2.x; o[2].y += a_ * f2.y; o[2].z += a_ * f2.z; o[2].w += a_ * f2.w; \
    o[3].x += a_ * f3.x; o[3].y += a_ * f3.y; o[3].z += a_ * f3.z; o[3].w += a_ * f3.w; \
  }

  // prologue: 2 tiles in flight (8 DMAs/wave)
  STAGE(0, 0);
  STAGE(1, 1);
#pragma unroll 1
  for (int nt = 0; nt < 30; ++nt) {
    asm volatile("s_waitcnt vmcnt(4)" ::: "memory");  // tile nt resident
    COMPUTE(nt & 1);
    STAGE(nt + 2, nt & 1);                            // refill consumed buf
  }
  asm volatile("s_waitcnt vmcnt(4)" ::: "memory");
  COMPUTE(0);   // tile 30
  asm volatile("s_waitcnt vmcnt(0)" ::: "memory");
  COMPUTE(1);   // tile 31
#undef STAGE
#undef COMPUTE

  // cross-group combine (groups hold disjoint slots, same d-fragments)
#pragma unroll
  for (int off = 16; off <= 32; off <<= 1) {
    lsum += __shfl_xor(lsum, off);
#pragma unroll
    for (int p = 0; p < 4; ++p) {
      o[p].x += __shfl_xor(o[p].x, off);
      o[p].y += __shfl_xor(o[p].y, off);
      o[p].z += __shfl_xor(o[p].z, off);
      o[p].w += __shfl_xor(o[p].w, off);
    }
  }
  if (g == 0) {
#pragma unroll
    for (int p = 0; p < 4; ++p) *(float4*)&wo[w][p * 64 + l * 4] = o[p];
    if (l == 0) wl[w] = lsum;
  }
  __syncthreads();
  const float od = wo[0][t] + wo[1][t] + wo[2][t] + wo[3][t];
  float* apo = att_part + (size_t)(b * 8 + ss) * 264;
  if (t == 0) apo[0] = wl[0] + wl[1] + wl[2] + wl[3];
  apo[4 + t] = od;
}

// ---------------------------------------------------------------------------
// K4a: combine split partials (plain sums) -> cand_att_vec; attention gate;
// build inp_cat[b][768] = [att_vec | x_cont | h_tm1].  grid 128, block 256.
// ---------------------------------------------------------------------------
__global__ __launch_bounds__(256) void k4a_gate(
    const float* __restrict__ att_part, const float* __restrict__ h_tm1,
    const float* __restrict__ x_cont, const float* __restrict__ Wg,
    const float* __restrict__ bg_, float* __restrict__ inp_cat) {
  const int b = blockIdx.x, t = threadIdx.x;
  const float* ap = att_part + (size_t)b * 8 * 264;
  float lg = 0.f, od = 0.f;
#pragma unroll
  for (int ss = 0; ss < 8; ++ss) {
    lg += ap[ss * 264];
    od += ap[ss * 264 + 4 + t];
  }
  const float cand = od / lg;
  const float hv = h_tm1[b * 256 + t];
  const float xc = x_cont[b * 256 + t];
  float v = cand * Wg[t] + hv * Wg[256 + t] + xc * Wg[512 + t];
  for (int off = 32; off; off >>= 1) v += __shfl_xor(v, off);
  __shared__ float rr[4];
  __shared__ float gsh;
  const int w_ = t >> 6, lane = t & 63;
  if (lane == 0) rr[w_] = v;
  __syncthreads();
  if (t == 0) {
    const float s = rr[0] + rr[1] + rr[2] + rr[3] + bg_[0];
    gsh = 1.f / (1.f + expf(-s));
  }
  __syncthreads();
  inp_cat[b * 768 + t] = cand * gsh;
  inp_cat[b * 768 + 256 + t] = xc;
  inp_cat[b * 768 + 512 + t] = hv;
}

// ---------------------------------------------------------------------------
// K4b: LSTM cell.  Block bj handles columns {j0, j0+1} x all 4 gates x 128 b,
// K = 768 ([att_vec,x_cont] via W_ih then h_tm1 via W_hh).  Fuses c/h update.
// grid 128, block 256.
// ---------------------------------------------------------------------------
__global__ __launch_bounds__(256) void k4b_lstm(
    const float* __restrict__ inp_cat, const float* __restrict__ Wih,
    const float* __restrict__ bih, const float* __restrict__ Whh,
    const float* __restrict__ bhh, const float* __restrict__ c_tm1,
    float* __restrict__ h_out, float* __restrict__ c_out) {
  const int j0 = blockIdx.x * 2;
  const int t = threadIdx.x;
  __shared__ float inp_s[128][132];
  __shared__ float w_s[8][132];
  const int b = t >> 1, half = t & 1;
  float acc[4] = {0.f, 0.f, 0.f, 0.f};
  for (int kc = 0; kc < 6; ++kc) {
    const int kbase = kc * 128;
    for (int q = t; q < 4096; q += 256) {     // 128 x 128 floats
      const int row = q >> 5, c4 = q & 31;
      *(float4*)&inp_s[row][c4 * 4] =
          *(const float4*)(inp_cat + (size_t)row * 768 + kbase + c4 * 4);
    }
    {                                          // 8 x 128 floats, one f4/thread
      const int row = t >> 5, c4 = t & 31;
      const int gate = row & 3;
      const int j = j0 + (row >> 2);
      const int og = gate * 256 + j;
      const int kg = kbase + c4 * 4;
      float4 v;
      if (kg < 512) v = *(const float4*)(Wih + (size_t)og * 512 + kg);
      else          v = *(const float4*)(Whh + (size_t)og * 256 + (kg - 512));
      *(float4*)&w_s[row][c4 * 4] = v;
    }
    __syncthreads();
    for (int k = 0; k < 128; k += 4) {
      const float4 iv = *(const float4*)&inp_s[b][k];
#pragma unroll
      for (int g = 0; g < 4; ++g) {
        const float4 wv = *(const float4*)&w_s[half * 4 + g][k];
        acc[g] += iv.x * wv.x + iv.y * wv.y + iv.z * wv.z + iv.w * wv.w;
      }
    }
    __syncthreads();
  }
  const int j = j0 + half;
  const float gi = acc[0] + bih[j] + bhh[j];
  const float gf = acc[1] + bih[256 + j] + bhh[256 + j];
  const float gg = acc[2] + bih[512 + j] + bhh[512 + j];
  const float go = acc[3] + bih[768 + j] + bhh[768 + j];
  const float ct = c_tm1[b * 256 + j];
  const float i_ = 1.f / (1.f + expf(-gi));
  const float f_ = 1.f / (1.f + expf(-gf));
  const float g_ = tanhf(gg);
  const float o_ = 1.f / (1.f + expf(-go));
  const float c = f_ * ct + i_ * g_;
  const float h = o_ * tanhf(c);
  h_out[b * 256 + j] = h;
  c_out[b * 256 + j] = c;
}

// ---------------------------------------------------------------------------
// K5: head hidden layers (post-relu).  grid 128 (batch), block 256
// (t<128 -> actor_hid, t>=128 -> critic_hid).
// ---------------------------------------------------------------------------
__global__ __launch_bounds__(256) void k5_hid(
    const float* __restrict__ h_in, const float* __restrict__ Wah,
    const float* __restrict__ bah, const float* __restrict__ Wch,
    const float* __restrict__ bch, float* __restrict__ hidA,
    float* __restrict__ hidC) {
  const int b = blockIdx.x, t = threadIdx.x;
  __shared__ float hs[256];
  hs[t] = h_in[b * 256 + t];
  __syncthreads();
  const float* W = (t < 128) ? (Wah + (size_t)t * 256) : (Wch + (size_t)(t - 128) * 256);
  float s = (t < 128) ? bah[t] : bch[t - 128];
  for (int k = 0; k < 256; k += 4) {
    const float4 w = *(const float4*)(W + k);
    s += hs[k] * w.x + hs[k + 1] * w.y + hs[k + 2] * w.z + hs[k + 3] * w.w;
  }
  s = fmaxf(s, 0.f);
  if (t < 128) hidA[b * 128 + t] = s;
  else         hidC[b * 128 + (t - 128)] = s;
}

// ---------------------------------------------------------------------------
// K6: action logits GEMM [128,10000] = hidA[128,128] @ W_actor^T + b.
// grid (158, 4): batch split 4x; (157,0) computes value.  XOR-swizzled LDS.
// ---------------------------------------------------------------------------
__global__ __launch_bounds__(256) void k6_heads(
    const float* __restrict__ hidA, const float* __restrict__ hidC,
    const float* __restrict__ Wa, const float* __restrict__ ba,
    const float* __restrict__ Wc, const float* __restrict__ bc,
    float* __restrict__ logits, float* __restrict__ value) {
  const int t = threadIdx.x;
  const int bx = blockIdx.x, by = blockIdx.y;
  if (bx == 157) {
    if (by == 0 && t < 128) {
      const float* hc = hidC + (size_t)t * 128;
      float s = bc[0];
      for (int k = 0; k < 128; k += 4) {
        const float4 w = *(const float4*)(Wc + k);
        s += hc[k] * w.x + hc[k + 1] * w.y + hc[k + 2] * w.z + hc[k + 3] * w.w;
      }
      value[t] = s;
    }
    return;
  }
  const int o0 = bx * 64;
  const int b0 = by * 32;
  __shared__ float4 ha[32][32];
  __shared__ float4 wa[64][32];
  for (int q = t; q < 1024; q += 256) {    // 32 rows x 32 f4
    const int row = q >> 5, c4 = q & 31;
    ha[row][c4 ^ ((row >> 2) & 7)] =
        *(const float4*)(hidA + (size_t)(b0 + row) * 128 + c4 * 4);
  }
  for (int q = t; q < 2048; q += 256) {    // 64 rows x 32 f4
    const int row = q >> 5, c4 = q & 31;
    const int o = o0 + row;
    float4 v = make_float4(0.f, 0.f, 0.f, 0.f);
    if (o < WN) v = *(const float4*)(Wa + (size_t)o * 128 + c4 * 4);
    wa[row][c4 ^ ((row >> 2) & 7)] = v;
  }
  __syncthreads();
  const int og = t & 15, bq = t >> 4;      // 16 out-groups x 16 batch-groups
  float acc[2][4];
#pragma unroll
  for (int r = 0; r < 2; ++r)
#pragma unroll
    for (int i = 0; i < 4; ++i) acc[r][i] = 0.f;
#pragma unroll 4
  for (int c4 = 0; c4 < 32; ++c4) {
    float4 wv[4];
#pragma unroll
    for (int i = 0; i < 4; ++i) wv[i] = wa[og * 4 + i][c4 ^ (og & 7)];
#pragma unroll
    for (int r = 0; r < 2; ++r) {
      const int row = bq * 2 + r;
      const float4 hv = ha[row][c4 ^ ((row >> 2) & 7)];
#pragma unroll
      for (int i = 0; i < 4; ++i)
        acc[r][i] += hv.x * wv[i].x + hv.y * wv[i].y + hv.z * wv[i].z + hv.w * wv[i].w;
    }
  }
  const int obase = o0 + og * 4;
#pragma unroll
  for (int r = 0; r < 2; ++r) {
    const int bb = b0 + bq * 2 + r;
    if (obase + 3 < WN) {
      const float4 bias = *(const float4*)(ba + obase);
      float4 res;
      res.x = acc[r][0] + bias.x;
      res.y = acc[r][1] + bias.y;
      res.z = acc[r][2] + bias.z;
      res.w = acc[r][3] + bias.w;
      *(float4*)(logits + (size_t)bb * WN + obase) = res;
    } else {
      for (int i = 0; i < 4; ++i)
        if (obase + i < WN) logits[(size_t)bb * WN + obase + i] = acc[r][i] + ba[obase + i];
    }
  }
}

// ---------------------------------------------------------------------------
extern "C" void kernel_launch(void* const* d_in, const int* in_sizes, int n_in,
                              void* d_out, int out_size, void* d_ws, size_t ws_size,
                              hipStream_t stream) {
  const float* x     = (const float*)d_in[0];
  const float* feat  = (const float*)d_in[1];
  const float* h_tm1 = (const float*)d_in[2];
  const float* c_tm1 = (const float*)d_in[3];
  const float* Wx2c  = (const float*)d_in[4];
  const float* bx2c  = (const float*)d_in[5];
  const float* Wh2c  = (const float*)d_in[6];
  const float* bh2c  = (const float*)d_in[7];
  const float* Wc2k  = (const float*)d_in[8];
  const float* bc2k  = (const float*)d_in[9];
  const float* Wc2s  = (const float*)d_in[10];
  const float* bc2s  = (const float*)d_in[11];
  const float* Wag   = (const float*)d_in[12];
  const float* bag   = (const float*)d_in[13];
  const float* Wih   = (const float*)d_in[14];
  const float* bih   = (const float*)d_in[15];
  const float* Whh   = (const float*)d_in[16];
  const float* bhh   = (const float*)d_in[17];
  const float* Wah   = (const float*)d_in[18];
  const float* bah   = (const float*)d_in[19];
  const float* Wch   = (const float*)d_in[20];
  const float* bch   = (const float*)d_in[21];
  const float* Wa    = (const float*)d_in[22];
  const float* ba    = (const float*)d_in[23];
  const float* Wc    = (const float*)d_in[24];
  const float* bc    = (const float*)d_in[25];

  float* out    = (float*)d_out;
  float* logits = out;                 // 1,280,000
  float* value  = out + 1280000;       // 128
  float* h_out  = out + 1280128;       // 32,768
  float* c_out  = out + 1312896;       // 32,768

  float* wsf      = (float*)d_ws;
  float* part     = wsf;               // 40*32768 = 1,310,720
  float* x_cont   = part + 1310720;    // 32,768
  float* key_v    = x_cont + 32768;    // 32,768
  float* strength = key_v + 32768;     // 128
  float* key_n    = strength + 128;    // 128
  float* att_part = key_n + 128;       // 128*8*264 = 270,336
  float* inp_cat  = att_part + 270336; // 128*768 = 98,304
  float* hidA     = inp_cat + 98304;   // 16,384
  float* hidC     = hidA + 16384;      // 16,384

  k1_xcont<<<dim3(16, 40), 256, 0, stream>>>(x, Wx2c, part);
  k2_controller<<<128, 256, 0, stream>>>(part, bx2c, h_tm1, Wh2c, bh2c,
                                         Wc2k, bc2k, Wc2s, bc2s,
                                         x_cont, key_v, strength, key_n);
  k3_attn<<<dim3(8, 128), 256, 0, stream>>>(feat, key_v, strength, key_n, att_part);
  k4a_gate<<<128, 256, 0, stream>>>(att_part, h_tm1, x_cont, Wag, bag, inp_cat);
  k4b_lstm<<<128, 256, 0, stream>>>(inp_cat, Wih, bih, Whh, bhh, c_tm1, h_out, c_out);
  k5_hid<<<128, 256, 0, stream>>>(h_out, Wah, bah, Wch, bch, hidA, hidC);
  k6_heads<<<dim3(158, 4), 256, 0, stream>>>(hidA, hidC, Wa, ba, Wc, bc, logits, value);
}

// Round 12
// 240.537 us; speedup vs baseline: 2.2073x; 1.1467x over previous
//
#include <hip/hip_runtime.h>
#include <cmath>

// Shapes
// B=128, S=4096, W_NUM=10000, CONT=FEAT=LSTM=256, AH=CH=128
// out = [logits 128*10000 | value 128 | h 128*256 | c 128*256]

#define B_ 128
#define S_ 4096
#define WN 10000
#define CD 256

// ---------------------------------------------------------------------------
// K1: x_cont partial GEMM.  part[ks][128,256-slice] = x[128,k-chunk] @ W^T.
// grid (16 n-tiles of 16, 40 k-chunks of 256), block 256.
// ---------------------------------------------------------------------------
__global__ __launch_bounds__(256) void k1_xcont(
    const float* __restrict__ x, const float* __restrict__ Wx,
    float* __restrict__ part) {
  const int nt = blockIdx.x;   // 0..15
  const int ks = blockIdx.y;   // 0..39
  const int t = threadIdx.x;
  __shared__ float4 xs[128][16];    // 128 rows x 64 k, XOR-swizzled
  __shared__ float4 wsW[16][16];
  const int o0 = nt * 16;
  const int og = t & 3;             // 4 output-groups of 4
  const int bg = t >> 2;            // 0..63 -> rows bg, bg+64
  const int bgx = bg & 7;
  float acc[2][4] = {{0.f, 0.f, 0.f, 0.f}, {0.f, 0.f, 0.f, 0.f}};
  for (int sub = 0; sub < 4; ++sub) {
    const int k0 = ks * 256 + sub * 64;
    for (int q = t; q < 2048; q += 256) {          // 128 x 16 f4
      const int row = q >> 4, c4 = q & 15;
      const int k = k0 + c4 * 4;
      float4 v = make_float4(0.f, 0.f, 0.f, 0.f);
      if (k < WN) v = *(const float4*)(x + (size_t)row * WN + k);
      xs[row][c4 ^ (row & 7)] = v;
    }
    {                                              // 16 x 16 f4, 1/thread
      const int row = t >> 4, c4 = t & 15;
      const int k = k0 + c4 * 4;
      float4 v = make_float4(0.f, 0.f, 0.f, 0.f);
      if (k < WN) v = *(const float4*)(Wx + (size_t)(o0 + row) * WN + k);
      wsW[row][c4 ^ (row & 7)] = v;
    }
    __syncthreads();
#pragma unroll
    for (int c4 = 0; c4 < 16; ++c4) {
      float4 wv[4];
#pragma unroll
      for (int i = 0; i < 4; ++i) wv[i] = wsW[og * 4 + i][c4 ^ ((og * 4 + i) & 7)];
#pragma unroll
      for (int j = 0; j < 2; ++j) {
        const float4 xv = xs[bg + j * 64][c4 ^ bgx];
#pragma unroll
        for (int i = 0; i < 4; ++i)
          acc[j][i] += xv.x * wv[i].x + xv.y * wv[i].y + xv.z * wv[i].z + xv.w * wv[i].w;
      }
    }
    __syncthreads();
  }
#pragma unroll
  for (int j = 0; j < 2; ++j) {
    const int bb = bg + j * 64;
#pragma unroll
    for (int i = 0; i < 4; ++i)
      part[(size_t)ks * 32768 + bb * 256 + o0 + og * 4 + i] = acc[j][i];
  }
}

// ---------------------------------------------------------------------------
// K2: reduce partials -> x_cont; controller: control, key_v, strength, key_n.
// grid 128 (batch), block 256 (output dim).
// ---------------------------------------------------------------------------
__global__ __launch_bounds__(256) void k2_controller(
    const float* __restrict__ part, const float* __restrict__ bx,
    const float* __restrict__ h_tm1, const float* __restrict__ Wh,
    const float* __restrict__ bh, const float* __restrict__ Wk,
    const float* __restrict__ bk, const float* __restrict__ Ws,
    const float* __restrict__ bs, float* __restrict__ x_cont,
    float* __restrict__ key_v, float* __restrict__ strength,
    float* __restrict__ key_n) {
  const int b = blockIdx.x, t = threadIdx.x;
  __shared__ float hs[256], cs[256];
  __shared__ float r1[4], r2[4];
  hs[t] = h_tm1[b * 256 + t];
  float xc = bx[t];
  for (int ks = 0; ks < 40; ++ks) xc += part[(size_t)ks * 32768 + b * 256 + t];
  x_cont[b * 256 + t] = xc;
  __syncthreads();
  float hc = bh[t];
  {
    const float* w = Wh + (size_t)t * 256;
    for (int k = 0; k < 256; k += 4) {
      float4 wv = *(const float4*)(w + k);
      hc += hs[k] * wv.x + hs[k + 1] * wv.y + hs[k + 2] * wv.z + hs[k + 3] * wv.w;
    }
  }
  const float ctl = fmaxf(xc + hc, 0.f);
  cs[t] = ctl;
  __syncthreads();
  float kvv = bk[t];
  {
    const float* w = Wk + (size_t)t * 256;
    for (int k = 0; k < 256; k += 4) {
      float4 wv = *(const float4*)(w + k);
      kvv += cs[k] * wv.x + cs[k + 1] * wv.y + cs[k + 2] * wv.z + cs[k + 3] * wv.w;
    }
  }
  kvv = tanhf(kvv);
  key_v[b * 256 + t] = kvv;
  float v1 = kvv * kvv;
  float v2 = ctl * Ws[t];
  for (int off = 32; off; off >>= 1) {
    v1 += __shfl_xor(v1, off);
    v2 += __shfl_xor(v2, off);
  }
  const int w_ = t >> 6, lane = t & 63;
  if (lane == 0) { r1[w_] = v1; r2[w_] = v2; }
  __syncthreads();
  if (t == 0) {
    const float n2 = r1[0] + r1[1] + r1[2] + r1[3];
    const float sd = r2[0] + r2[1] + r2[2] + r2[3];
    key_n[b] = sqrtf(n2);
    strength[b] = fmaxf(sd + bs[0], 0.f) + 1.f;
  }
}

// ---------------------------------------------------------------------------
// DPP 16-lane butterfly sum via row_ror (pure VALU, no DS pipe).
// ---------------------------------------------------------------------------
__device__ __forceinline__ float dpp_add16(float x) {
  int t;
  t = __builtin_amdgcn_update_dpp(0, __float_as_int(x), 0x121, 0xf, 0xf, true);
  x += __int_as_float(t);   // ror:1
  t = __builtin_amdgcn_update_dpp(0, __float_as_int(x), 0x122, 0xf, 0xf, true);
  x += __int_as_float(t);   // ror:2
  t = __builtin_amdgcn_update_dpp(0, __float_as_int(x), 0x124, 0xf, 0xf, true);
  x += __int_as_float(t);   // ror:4
  t = __builtin_amdgcn_update_dpp(0, __float_as_int(x), 0x128, 0xf, 0xf, true);
  x += __int_as_float(t);   // ror:8
  return x;
}

// ---------------------------------------------------------------------------
// K3: content attention, fixed-shift softmax (score < str since |cos|<1).
// R10/R11 elimination: schedule, reduce pipe, prefetch depth, occupancy all
// null; invariant = HBM read rate ~3.4 TB/s while fills WRITE at 6.77 TB/s.
// Theory: 537MB stream misses L3 100% and ALLOCATES every line -> L3 ingest
// is the cap.  THIS ROUND: non-temporal DMA (aux=2 = CPol NT on gfx950) --
// feat bytes are read exactly once, NT skips cache allocation.
// Structure unchanged from R11: 2-buf ring, counted vmcnt, DPP, 4 blocks/CU,
// grid (8 s-splits, 128 batch), block 256 = 4 waves; 16-lane group per slot.
// ---------------------------------------------------------------------------
__global__ __launch_bounds__(256) void k3_attn(
    const float* __restrict__ feat, const float* __restrict__ key_v,
    const float* __restrict__ strength, const float* __restrict__ key_n,
    float* __restrict__ att_part) {
  const int ss = blockIdx.x;   // 0..7
  const int b = blockIdx.y;    // 0..127
  const int t = threadIdx.x;
  const int w = t >> 6, lane = t & 63;
  const int g = lane >> 4;     // group (slot within wave-quad)
  const int l = lane & 15;     // lane in group

  __shared__ __align__(16) float tile[2][16][256];   // 32 KB double buffer
  __shared__ float wo[4][256];
  __shared__ float wl[4];

  const float str = strength[b];
  const float kn = key_n[b];
  float4 kf[4];
#pragma unroll
  for (int p = 0; p < 4; ++p)
    kf[p] = *(const float4*)(key_v + b * 256 + p * 64 + l * 4);

  const float* fbase = feat + ((size_t)b * S_ + (size_t)ss * 512) * 256;

  // wave w DMA-stages ITS OWN rows w*4..w*4+3 of tile nt (1 row = 1 instr)
  // aux=2: CPol NT (non-temporal) -- skip cache allocation for the stream.
#define STAGE(nt, buf)                                                        \
  {                                                                           \
    _Pragma("unroll") for (int j = 0; j < 4; ++j) {                           \
      const int row_ = w * 4 + j;                                             \
      const float* gp_ = fbase + ((size_t)(nt)*16 + row_) * 256 + lane * 4;   \
      __builtin_amdgcn_global_load_lds(                                       \
          (const __attribute__((address_space(1))) void*)gp_,                 \
          (__attribute__((address_space(3))) void*)&tile[buf][row_][0], 16,   \
          0, 2);                                                              \
    }                                                                         \
  }

  float4 o[4];
#pragma unroll
  for (int p = 0; p < 4; ++p) o[p] = make_float4(0.f, 0.f, 0.f, 0.f);
  float lsum = 0.f;

  // wave w consumes row w*4+g of the given ring buffer (its own staged rows)
#define COMPUTE(buf)                                                          \
  {                                                                           \
    const int row_ = w * 4 + g;                                               \
    const float* rp_ = &tile[buf][row_][l * 4];                               \
    const float4 f0 = *(const float4*)(rp_);                                  \
    const float4 f1 = *(const float4*)(rp_ + 64);                             \
    const float4 f2 = *(const float4*)(rp_ + 128);                            \
    const float4 f3 = *(const float4*)(rp_ + 192);                            \
    float dp0 = f0.x * kf[0].x + f0.y * kf[0].y + f0.z * kf[0].z + f0.w * kf[0].w; \
    float dp1 = f1.x * kf[1].x + f1.y * kf[1].y + f1.z * kf[1].z + f1.w * kf[1].w; \
    float dp2 = f2.x * kf[2].x + f2.y * kf[2].y + f2.z * kf[2].z + f2.w * kf[2].w; \
    float dp3 = f3.x * kf[3].x + f3.y * kf[3].y + f3.z * kf[3].z + f3.w * kf[3].w; \
    float nn0 = f0.x * f0.x + f0.y * f0.y + f0.z * f0.z + f0.w * f0.w;        \
    float nn1 = f1.x * f1.x + f1.y * f1.y + f1.z * f1.z + f1.w * f1.w;        \
    float nn2 = f2.x * f2.x + f2.y * f2.y + f2.z * f2.z + f2.w * f2.w;        \
    float nn3 = f3.x * f3.x + f3.y * f3.y + f3.z * f3.z + f3.w * f3.w;        \
    float d_ = (dp0 + dp1) + (dp2 + dp3);                                     \
    float n2_ = (nn0 + nn1) + (nn2 + nn3);                                    \
    d_ = dpp_add16(d_);                                                       \
    n2_ = dpp_add16(n2_);                                                     \
    const float sc_ = str * d_ / (sqrtf(n2_) * kn + 1e-8f);                   \
    const float a_ = __expf(sc_ - str);                                       \
    lsum += a_;                                                               \
    o[0].x += a_ * f0.x; o[0].y += a_ * f0.y; o[0].z += a_ * f0.z; o[0].w += a_ * f0.w; \
    o[1].x += a_ * f1.x; o[1].y += a_ * f1.y; o[1].z += a_ * f1.z; o[1].w += a_ * f1.w; \
    o[2].x += a_ * f2.x; o[2].y += a_ * f2.y; o[2].z += a_ * f2.z; o[2].w += a_ * f2.w; \
    o[3].x += a_ * f3.x; o[3].y += a_ * f3.y; o[3].z += a_ * f3.z; o[3].w += a_ * f3.w; \
  }

  // prologue: 2 tiles in flight (8 DMAs/wave)
  STAGE(0, 0);
  STAGE(1, 1);
#pragma unroll 1
  for (int nt = 0; nt < 30; ++nt) {
    asm volatile("s_waitcnt vmcnt(4)" ::: "memory");  // tile nt resident
    COMPUTE(nt & 1);
    STAGE(nt + 2, nt & 1);                            // refill consumed buf
  }
  asm volatile("s_waitcnt vmcnt(4)" ::: "memory");
  COMPUTE(0);   // tile 30
  asm volatile("s_waitcnt vmcnt(0)" ::: "memory");
  COMPUTE(1);   // tile 31
#undef STAGE
#undef COMPUTE

  // cross-group combine (groups hold disjoint slots, same d-fragments)
#pragma unroll
  for (int off = 16; off <= 32; off <<= 1) {
    lsum += __shfl_xor(lsum, off);
#pragma unroll
    for (int p = 0; p < 4; ++p) {
      o[p].x += __shfl_xor(o[p].x, off);
      o[p].y += __shfl_xor(o[p].y, off);
      o[p].z += __shfl_xor(o[p].z, off);
      o[p].w += __shfl_xor(o[p].w, off);
    }
  }
  if (g == 0) {
#pragma unroll
    for (int p = 0; p < 4; ++p) *(float4*)&wo[w][p * 64 + l * 4] = o[p];
    if (l == 0) wl[w] = lsum;
  }
  __syncthreads();
  const float od = wo[0][t] + wo[1][t] + wo[2][t] + wo[3][t];
  float* apo = att_part + (size_t)(b * 8 + ss) * 264;
  if (t == 0) apo[0] = wl[0] + wl[1] + wl[2] + wl[3];
  apo[4 + t] = od;
}

// ---------------------------------------------------------------------------
// K4a: combine split partials (plain sums) -> cand_att_vec; attention gate;
// build inp_cat[b][768] = [att_vec | x_cont | h_tm1].  grid 128, block 256.
// ---------------------------------------------------------------------------
__global__ __launch_bounds__(256) void k4a_gate(
    const float* __restrict__ att_part, const float* __restrict__ h_tm1,
    const float* __restrict__ x_cont, const float* __restrict__ Wg,
    const float* __restrict__ bg_, float* __restrict__ inp_cat) {
  const int b = blockIdx.x, t = threadIdx.x;
  const float* ap = att_part + (size_t)b * 8 * 264;
  float lg = 0.f, od = 0.f;
#pragma unroll
  for (int ss = 0; ss < 8; ++ss) {
    lg += ap[ss * 264];
    od += ap[ss * 264 + 4 + t];
  }
  const float cand = od / lg;
  const float hv = h_tm1[b * 256 + t];
  const float xc = x_cont[b * 256 + t];
  float v = cand * Wg[t] + hv * Wg[256 + t] + xc * Wg[512 + t];
  for (int off = 32; off; off >>= 1) v += __shfl_xor(v, off);
  __shared__ float rr[4];
  __shared__ float gsh;
  const int w_ = t >> 6, lane = t & 63;
  if (lane == 0) rr[w_] = v;
  __syncthreads();
  if (t == 0) {
    const float s = rr[0] + rr[1] + rr[2] + rr[3] + bg_[0];
    gsh = 1.f / (1.f + expf(-s));
  }
  __syncthreads();
  inp_cat[b * 768 + t] = cand * gsh;
  inp_cat[b * 768 + 256 + t] = xc;
  inp_cat[b * 768 + 512 + t] = hv;
}

// ---------------------------------------------------------------------------
// K4b: LSTM cell.  Block bj handles columns {j0, j0+1} x all 4 gates x 128 b,
// K = 768 ([att_vec,x_cont] via W_ih then h_tm1 via W_hh).  Fuses c/h update.
// grid 128, block 256.
// ---------------------------------------------------------------------------
__global__ __launch_bounds__(256) void k4b_lstm(
    const float* __restrict__ inp_cat, const float* __restrict__ Wih,
    const float* __restrict__ bih, const float* __restrict__ Whh,
    const float* __restrict__ bhh, const float* __restrict__ c_tm1,
    float* __restrict__ h_out, float* __restrict__ c_out) {
  const int j0 = blockIdx.x * 2;
  const int t = threadIdx.x;
  __shared__ float inp_s[128][132];
  __shared__ float w_s[8][132];
  const int b = t >> 1, half = t & 1;
  float acc[4] = {0.f, 0.f, 0.f, 0.f};
  for (int kc = 0; kc < 6; ++kc) {
    const int kbase = kc * 128;
    for (int q = t; q < 4096; q += 256) {     // 128 x 128 floats
      const int row = q >> 5, c4 = q & 31;
      *(float4*)&inp_s[row][c4 * 4] =
          *(const float4*)(inp_cat + (size_t)row * 768 + kbase + c4 * 4);
    }
    {                                          // 8 x 128 floats, one f4/thread
      const int row = t >> 5, c4 = t & 31;
      const int gate = row & 3;
      const int j = j0 + (row >> 2);
      const int og = gate * 256 + j;
      const int kg = kbase + c4 * 4;
      float4 v;
      if (kg < 512) v = *(const float4*)(Wih + (size_t)og * 512 + kg);
      else          v = *(const float4*)(Whh + (size_t)og * 256 + (kg - 512));
      *(float4*)&w_s[row][c4 * 4] = v;
    }
    __syncthreads();
    for (int k = 0; k < 128; k += 4) {
      const float4 iv = *(const float4*)&inp_s[b][k];
#pragma unroll
      for (int g = 0; g < 4; ++g) {
        const float4 wv = *(const float4*)&w_s[half * 4 + g][k];
        acc[g] += iv.x * wv.x + iv.y * wv.y + iv.z * wv.z + iv.w * wv.w;
      }
    }
    __syncthreads();
  }
  const int j = j0 + half;
  const float gi = acc[0] + bih[j] + bhh[j];
  const float gf = acc[1] + bih[256 + j] + bhh[256 + j];
  const float gg = acc[2] + bih[512 + j] + bhh[512 + j];
  const float go = acc[3] + bih[768 + j] + bhh[768 + j];
  const float ct = c_tm1[b * 256 + j];
  const float i_ = 1.f / (1.f + expf(-gi));
  const float f_ = 1.f / (1.f + expf(-gf));
  const float g_ = tanhf(gg);
  const float o_ = 1.f / (1.f + expf(-go));
  const float c = f_ * ct + i_ * g_;
  const float h = o_ * tanhf(c);
  h_out[b * 256 + j] = h;
  c_out[b * 256 + j] = c;
}

// ---------------------------------------------------------------------------
// K5: head hidden layers (post-relu).  grid 128 (batch), block 256
// (t<128 -> actor_hid, t>=128 -> critic_hid).
// ---------------------------------------------------------------------------
__global__ __launch_bounds__(256) void k5_hid(
    const float* __restrict__ h_in, const float* __restrict__ Wah,
    const float* __restrict__ bah, const float* __restrict__ Wch,
    const float* __restrict__ bch, float* __restrict__ hidA,
    float* __restrict__ hidC) {
  const int b = blockIdx.x, t = threadIdx.x;
  __shared__ float hs[256];
  hs[t] = h_in[b * 256 + t];
  __syncthreads();
  const float* W = (t < 128) ? (Wah + (size_t)t * 256) : (Wch + (size_t)(t - 128) * 256);
  float s = (t < 128) ? bah[t] : bch[t - 128];
  for (int k = 0; k < 256; k += 4) {
    const float4 w = *(const float4*)(W + k);
    s += hs[k] * w.x + hs[k + 1] * w.y + hs[k + 2] * w.z + hs[k + 3] * w.w;
  }
  s = fmaxf(s, 0.f);
  if (t < 128) hidA[b * 128 + t] = s;
  else         hidC[b * 128 + (t - 128)] = s;
}

// ---------------------------------------------------------------------------
// K6: action logits GEMM [128,10000] = hidA[128,128] @ W_actor^T + b.
// grid (158, 4): batch split 4x; (157,0) computes value.  XOR-swizzled LDS.
// ---------------------------------------------------------------------------
__global__ __launch_bounds__(256) void k6_heads(
    const float* __restrict__ hidA, const float* __restrict__ hidC,
    const float* __restrict__ Wa, const float* __restrict__ ba,
    const float* __restrict__ Wc, const float* __restrict__ bc,
    float* __restrict__ logits, float* __restrict__ value) {
  const int t = threadIdx.x;
  const int bx = blockIdx.x, by = blockIdx.y;
  if (bx == 157) {
    if (by == 0 && t < 128) {
      const float* hc = hidC + (size_t)t * 128;
      float s = bc[0];
      for (int k = 0; k < 128; k += 4) {
        const float4 w = *(const float4*)(Wc + k);
        s += hc[k] * w.x + hc[k + 1] * w.y + hc[k + 2] * w.z + hc[k + 3] * w.w;
      }
      value[t] = s;
    }
    return;
  }
  const int o0 = bx * 64;
  const int b0 = by * 32;
  __shared__ float4 ha[32][32];
  __shared__ float4 wa[64][32];
  for (int q = t; q < 1024; q += 256) {    // 32 rows x 32 f4
    const int row = q >> 5, c4 = q & 31;
    ha[row][c4 ^ ((row >> 2) & 7)] =
        *(const float4*)(hidA + (size_t)(b0 + row) * 128 + c4 * 4);
  }
  for (int q = t; q < 2048; q += 256) {    // 64 rows x 32 f4
    const int row = q >> 5, c4 = q & 31;
    const int o = o0 + row;
    float4 v = make_float4(0.f, 0.f, 0.f, 0.f);
    if (o < WN) v = *(const float4*)(Wa + (size_t)o * 128 + c4 * 4);
    wa[row][c4 ^ ((row >> 2) & 7)] = v;
  }
  __syncthreads();
  const int og = t & 15, bq = t >> 4;      // 16 out-groups x 16 batch-groups
  float acc[2][4];
#pragma unroll
  for (int r = 0; r < 2; ++r)
#pragma unroll
    for (int i = 0; i < 4; ++i) acc[r][i] = 0.f;
#pragma unroll 4
  for (int c4 = 0; c4 < 32; ++c4) {
    float4 wv[4];
#pragma unroll
    for (int i = 0; i < 4; ++i) wv[i] = wa[og * 4 + i][c4 ^ (og & 7)];
#pragma unroll
    for (int r = 0; r < 2; ++r) {
      const int row = bq * 2 + r;
      const float4 hv = ha[row][c4 ^ ((row >> 2) & 7)];
#pragma unroll
      for (int i = 0; i < 4; ++i)
        acc[r][i] += hv.x * wv[i].x + hv.y * wv[i].y + hv.z * wv[i].z + hv.w * wv[i].w;
    }
  }
  const int obase = o0 + og * 4;
#pragma unroll
  for (int r = 0; r < 2; ++r) {
    const int bb = b0 + bq * 2 + r;
    if (obase + 3 < WN) {
      const float4 bias = *(const float4*)(ba + obase);
      float4 res;
      res.x = acc[r][0] + bias.x;
      res.y = acc[r][1] + bias.y;
      res.z = acc[r][2] + bias.z;
      res.w = acc[r][3] + bias.w;
      *(float4*)(logits + (size_t)bb * WN + obase) = res;
    } else {
      for (int i = 0; i < 4; ++i)
        if (obase + i < WN) logits[(size_t)bb * WN + obase + i] = acc[r][i] + ba[obase + i];
    }
  }
}

// ---------------------------------------------------------------------------
extern "C" void kernel_launch(void* const* d_in, const int* in_sizes, int n_in,
                              void* d_out, int out_size, void* d_ws, size_t ws_size,
                              hipStream_t stream) {
  const float* x     = (const float*)d_in[0];
  const float* feat  = (const float*)d_in[1];
  const float* h_tm1 = (const float*)d_in[2];
  const float* c_tm1 = (const float*)d_in[3];
  const float* Wx2c  = (const float*)d_in[4];
  const float* bx2c  = (const float*)d_in[5];
  const float* Wh2c  = (const float*)d_in[6];
  const float* bh2c  = (const float*)d_in[7];
  const float* Wc2k  = (const float*)d_in[8];
  const float* bc2k  = (const float*)d_in[9];
  const float* Wc2s  = (const float*)d_in[10];
  const float* bc2s  = (const float*)d_in[11];
  const float* Wag   = (const float*)d_in[12];
  const float* bag   = (const float*)d_in[13];
  const float* Wih   = (const float*)d_in[14];
  const float* bih   = (const float*)d_in[15];
  const float* Whh   = (const float*)d_in[16];
  const float* bhh   = (const float*)d_in[17];
  const float* Wah   = (const float*)d_in[18];
  const float* bah   = (const float*)d_in[19];
  const float* Wch   = (const float*)d_in[20];
  const float* bch   = (const float*)d_in[21];
  const float* Wa    = (const float*)d_in[22];
  const float* ba    = (const float*)d_in[23];
  const float* Wc    = (const float*)d_in[24];
  const float* bc    = (const float*)d_in[25];

  float* out    = (float*)d_out;
  float* logits = out;                 // 1,280,000
  float* value  = out + 1280000;       // 128
  float* h_out  = out + 1280128;       // 32,768
  float* c_out  = out + 1312896;       // 32,768

  float* wsf      = (float*)d_ws;
  float* part     = wsf;               // 40*32768 = 1,310,720
  float* x_cont   = part + 1310720;    // 32,768
  float* key_v    = x_cont + 32768;    // 32,768
  float* strength = key_v + 32768;     // 128
  float* key_n    = strength + 128;    // 128
  float* att_part = key_n + 128;       // 128*8*264 = 270,336
  float* inp_cat  = att_part + 270336; // 128*768 = 98,304
  float* hidA     = inp_cat + 98304;   // 16,384
  float* hidC     = hidA + 16384;      // 16,384

  k1_xcont<<<dim3(16, 40), 256, 0, stream>>>(x, Wx2c, part);
  k2_controller<<<128, 256, 0, stream>>>(part, bx2c, h_tm1, Wh2c, bh2c,
                                         Wc2k, bc2k, Wc2s, bc2s,
                                         x_cont, key_v, strength, key_n);
  k3_attn<<<dim3(8, 128), 256, 0, stream>>>(feat, key_v, strength, key_n, att_part);
  k4a_gate<<<128, 256, 0, stream>>>(att_part, h_tm1, x_cont, Wag, bag, inp_cat);
  k4b_lstm<<<128, 256, 0, stream>>>(inp_cat, Wih, bih, Whh, bhh, c_tm1, h_out, c_out);
  k5_hid<<<128, 256, 0, stream>>>(h_out, Wah, bah, Wch, bch, hidA, hidC);
  k6_heads<<<dim3(158, 4), 256, 0, stream>>>(hidA, hidC, Wa, ba, Wc, bc, logits, value);
}

// Round 13
// 240.526 us; speedup vs baseline: 2.2074x; 1.0000x over previous
//
#include <hip/hip_runtime.h>
#include <cmath>

// Shapes
// B=128, S=4096, W_NUM=10000, CONT=FEAT=LSTM=256, AH=CH=128
// out = [logits 128*10000 | value 128 | h 128*256 | c 128*256]

#define B_ 128
#define S_ 4096
#define WN 10000
#define CD 256

// ---------------------------------------------------------------------------
// K1: x_cont partial GEMM.  part[ks][128,256-slice] = x[128,k-chunk] @ W^T.
// grid (16 n-tiles of 16, 40 k-chunks of 256), block 256.
// ---------------------------------------------------------------------------
__global__ __launch_bounds__(256) void k1_xcont(
    const float* __restrict__ x, const float* __restrict__ Wx,
    float* __restrict__ part) {
  const int nt = blockIdx.x;   // 0..15
  const int ks = blockIdx.y;   // 0..39
  const int t = threadIdx.x;
  __shared__ float4 xs[128][16];    // 128 rows x 64 k, XOR-swizzled
  __shared__ float4 wsW[16][16];
  const int o0 = nt * 16;
  const int og = t & 3;             // 4 output-groups of 4
  const int bg = t >> 2;            // 0..63 -> rows bg, bg+64
  const int bgx = bg & 7;
  float acc[2][4] = {{0.f, 0.f, 0.f, 0.f}, {0.f, 0.f, 0.f, 0.f}};
  for (int sub = 0; sub < 4; ++sub) {
    const int k0 = ks * 256 + sub * 64;
    for (int q = t; q < 2048; q += 256) {          // 128 x 16 f4
      const int row = q >> 4, c4 = q & 15;
      const int k = k0 + c4 * 4;
      float4 v = make_float4(0.f, 0.f, 0.f, 0.f);
      if (k < WN) v = *(const float4*)(x + (size_t)row * WN + k);
      xs[row][c4 ^ (row & 7)] = v;
    }
    {                                              // 16 x 16 f4, 1/thread
      const int row = t >> 4, c4 = t & 15;
      const int k = k0 + c4 * 4;
      float4 v = make_float4(0.f, 0.f, 0.f, 0.f);
      if (k < WN) v = *(const float4*)(Wx + (size_t)(o0 + row) * WN + k);
      wsW[row][c4 ^ (row & 7)] = v;
    }
    __syncthreads();
#pragma unroll
    for (int c4 = 0; c4 < 16; ++c4) {
      float4 wv[4];
#pragma unroll
      for (int i = 0; i < 4; ++i) wv[i] = wsW[og * 4 + i][c4 ^ ((og * 4 + i) & 7)];
#pragma unroll
      for (int j = 0; j < 2; ++j) {
        const float4 xv = xs[bg + j * 64][c4 ^ bgx];
#pragma unroll
        for (int i = 0; i < 4; ++i)
          acc[j][i] += xv.x * wv[i].x + xv.y * wv[i].y + xv.z * wv[i].z + xv.w * wv[i].w;
      }
    }
    __syncthreads();
  }
#pragma unroll
  for (int j = 0; j < 2; ++j) {
    const int bb = bg + j * 64;
#pragma unroll
    for (int i = 0; i < 4; ++i)
      part[(size_t)ks * 32768 + bb * 256 + o0 + og * 4 + i] = acc[j][i];
  }
}

// ---------------------------------------------------------------------------
// K2: reduce partials -> x_cont; controller: control, key_v, strength, key_n.
// grid 128 (batch), block 256 (output dim).
// ---------------------------------------------------------------------------
__global__ __launch_bounds__(256) void k2_controller(
    const float* __restrict__ part, const float* __restrict__ bx,
    const float* __restrict__ h_tm1, const float* __restrict__ Wh,
    const float* __restrict__ bh, const float* __restrict__ Wk,
    const float* __restrict__ bk, const float* __restrict__ Ws,
    const float* __restrict__ bs, float* __restrict__ x_cont,
    float* __restrict__ key_v, float* __restrict__ strength,
    float* __restrict__ key_n) {
  const int b = blockIdx.x, t = threadIdx.x;
  __shared__ float hs[256], cs[256];
  __shared__ float r1[4], r2[4];
  hs[t] = h_tm1[b * 256 + t];
  float xc = bx[t];
  for (int ks = 0; ks < 40; ++ks) xc += part[(size_t)ks * 32768 + b * 256 + t];
  x_cont[b * 256 + t] = xc;
  __syncthreads();
  float hc = bh[t];
  {
    const float* w = Wh + (size_t)t * 256;
    for (int k = 0; k < 256; k += 4) {
      float4 wv = *(const float4*)(w + k);
      hc += hs[k] * wv.x + hs[k + 1] * wv.y + hs[k + 2] * wv.z + hs[k + 3] * wv.w;
    }
  }
  const float ctl = fmaxf(xc + hc, 0.f);
  cs[t] = ctl;
  __syncthreads();
  float kvv = bk[t];
  {
    const float* w = Wk + (size_t)t * 256;
    for (int k = 0; k < 256; k += 4) {
      float4 wv = *(const float4*)(w + k);
      kvv += cs[k] * wv.x + cs[k + 1] * wv.y + cs[k + 2] * wv.z + cs[k + 3] * wv.w;
    }
  }
  kvv = tanhf(kvv);
  key_v[b * 256 + t] = kvv;
  float v1 = kvv * kvv;
  float v2 = ctl * Ws[t];
  for (int off = 32; off; off >>= 1) {
    v1 += __shfl_xor(v1, off);
    v2 += __shfl_xor(v2, off);
  }
  const int w_ = t >> 6, lane = t & 63;
  if (lane == 0) { r1[w_] = v1; r2[w_] = v2; }
  __syncthreads();
  if (t == 0) {
    const float n2 = r1[0] + r1[1] + r1[2] + r1[3];
    const float sd = r2[0] + r2[1] + r2[2] + r2[3];
    key_n[b] = sqrtf(n2);
    strength[b] = fmaxf(sd + bs[0], 0.f) + 1.f;
  }
}

// ---------------------------------------------------------------------------
// DPP 16-lane butterfly sum via row_ror (pure VALU, no DS pipe).
// ---------------------------------------------------------------------------
__device__ __forceinline__ float dpp_add16(float x) {
  int t;
  t = __builtin_amdgcn_update_dpp(0, __float_as_int(x), 0x121, 0xf, 0xf, true);
  x += __int_as_float(t);   // ror:1
  t = __builtin_amdgcn_update_dpp(0, __float_as_int(x), 0x122, 0xf, 0xf, true);
  x += __int_as_float(t);   // ror:2
  t = __builtin_amdgcn_update_dpp(0, __float_as_int(x), 0x124, 0xf, 0xf, true);
  x += __int_as_float(t);   // ror:4
  t = __builtin_amdgcn_update_dpp(0, __float_as_int(x), 0x128, 0xf, 0xf, true);
  x += __int_as_float(t);   // ror:8
  return x;
}

// ---------------------------------------------------------------------------
// K3: content attention, fixed-shift softmax (score < str since |cos|<1).
// R12 CONFIRMED: NT DMA (aux=2) cut K3 ~155 -> ~122us (-32.5 total) -- the
// 537MB single-use stream was throttled by Infinity-Cache line allocation.
// THIS ROUND: aux 2 -> 18 (NT | SC1): extend the no-allocate/streaming
// policy to device scope so the per-XCD L2 (4MB, equally thrashed by the
// stream) also stops allocating.  feat has zero reuse at any cache level.
// Structure unchanged: 2-buf ring, counted vmcnt, DPP, 4 blocks/CU,
// grid (8 s-splits, 128 batch), block 256 = 4 waves; 16-lane group per slot.
// ---------------------------------------------------------------------------
__global__ __launch_bounds__(256) void k3_attn(
    const float* __restrict__ feat, const float* __restrict__ key_v,
    const float* __restrict__ strength, const float* __restrict__ key_n,
    float* __restrict__ att_part) {
  const int ss = blockIdx.x;   // 0..7
  const int b = blockIdx.y;    // 0..127
  const int t = threadIdx.x;
  const int w = t >> 6, lane = t & 63;
  const int g = lane >> 4;     // group (slot within wave-quad)
  const int l = lane & 15;     // lane in group

  __shared__ __align__(16) float tile[2][16][256];   // 32 KB double buffer
  __shared__ float wo[4][256];
  __shared__ float wl[4];

  const float str = strength[b];
  const float kn = key_n[b];
  float4 kf[4];
#pragma unroll
  for (int p = 0; p < 4; ++p)
    kf[p] = *(const float4*)(key_v + b * 256 + p * 64 + l * 4);

  const float* fbase = feat + ((size_t)b * S_ + (size_t)ss * 512) * 256;

  // wave w DMA-stages ITS OWN rows w*4..w*4+3 of tile nt (1 row = 1 instr)
  // aux=18: CPol NT|SC1 -- non-temporal at device scope (skip L2+L3 alloc).
#define STAGE(nt, buf)                                                        \
  {                                                                           \
    _Pragma("unroll") for (int j = 0; j < 4; ++j) {                           \
      const int row_ = w * 4 + j;                                             \
      const float* gp_ = fbase + ((size_t)(nt)*16 + row_) * 256 + lane * 4;   \
      __builtin_amdgcn_global_load_lds(                                       \
          (const __attribute__((address_space(1))) void*)gp_,                 \
          (__attribute__((address_space(3))) void*)&tile[buf][row_][0], 16,   \
          0, 18);                                                             \
    }                                                                         \
  }

  float4 o[4];
#pragma unroll
  for (int p = 0; p < 4; ++p) o[p] = make_float4(0.f, 0.f, 0.f, 0.f);
  float lsum = 0.f;

  // wave w consumes row w*4+g of the given ring buffer (its own staged rows)
#define COMPUTE(buf)                                                          \
  {                                                                           \
    const int row_ = w * 4 + g;                                               \
    const float* rp_ = &tile[buf][row_][l * 4];                               \
    const float4 f0 = *(const float4*)(rp_);                                  \
    const float4 f1 = *(const float4*)(rp_ + 64);                             \
    const float4 f2 = *(const float4*)(rp_ + 128);                            \
    const float4 f3 = *(const float4*)(rp_ + 192);                            \
    float dp0 = f0.x * kf[0].x + f0.y * kf[0].y + f0.z * kf[0].z + f0.w * kf[0].w; \
    float dp1 = f1.x * kf[1].x + f1.y * kf[1].y + f1.z * kf[1].z + f1.w * kf[1].w; \
    float dp2 = f2.x * kf[2].x + f2.y * kf[2].y + f2.z * kf[2].z + f2.w * kf[2].w; \
    float dp3 = f3.x * kf[3].x + f3.y * kf[3].y + f3.z * kf[3].z + f3.w * kf[3].w; \
    float nn0 = f0.x * f0.x + f0.y * f0.y + f0.z * f0.z + f0.w * f0.w;        \
    float nn1 = f1.x * f1.x + f1.y * f1.y + f1.z * f1.z + f1.w * f1.w;        \
    float nn2 = f2.x * f2.x + f2.y * f2.y + f2.z * f2.z + f2.w * f2.w;        \
    float nn3 = f3.x * f3.x + f3.y * f3.y + f3.z * f3.z + f3.w * f3.w;        \
    float d_ = (dp0 + dp1) + (dp2 + dp3);                                     \
    float n2_ = (nn0 + nn1) + (nn2 + nn3);                                    \
    d_ = dpp_add16(d_);                                                       \
    n2_ = dpp_add16(n2_);                                                     \
    const float sc_ = str * d_ / (sqrtf(n2_) * kn + 1e-8f);                   \
    const float a_ = __expf(sc_ - str);                                       \
    lsum += a_;                                                               \
    o[0].x += a_ * f0.x; o[0].y += a_ * f0.y; o[0].z += a_ * f0.z; o[0].w += a_ * f0.w; \
    o[1].x += a_ * f1.x; o[1].y += a_ * f1.y; o[1].z += a_ * f1.z; o[1].w += a_ * f1.w; \
    o[2].x += a_ * f2.x; o[2].y += a_ * f2.y; o[2].z += a_ * f2.z; o[2].w += a_ * f2.w; \
    o[3].x += a_ * f3.x; o[3].y += a_ * f3.y; o[3].z += a_ * f3.z; o[3].w += a_ * f3.w; \
  }

  // prologue: 2 tiles in flight (8 DMAs/wave)
  STAGE(0, 0);
  STAGE(1, 1);
#pragma unroll 1
  for (int nt = 0; nt < 30; ++nt) {
    asm volatile("s_waitcnt vmcnt(4)" ::: "memory");  // tile nt resident
    COMPUTE(nt & 1);
    STAGE(nt + 2, nt & 1);                            // refill consumed buf
  }
  asm volatile("s_waitcnt vmcnt(4)" ::: "memory");
  COMPUTE(0);   // tile 30
  asm volatile("s_waitcnt vmcnt(0)" ::: "memory");
  COMPUTE(1);   // tile 31
#undef STAGE
#undef COMPUTE

  // cross-group combine (groups hold disjoint slots, same d-fragments)
#pragma unroll
  for (int off = 16; off <= 32; off <<= 1) {
    lsum += __shfl_xor(lsum, off);
#pragma unroll
    for (int p = 0; p < 4; ++p) {
      o[p].x += __shfl_xor(o[p].x, off);
      o[p].y += __shfl_xor(o[p].y, off);
      o[p].z += __shfl_xor(o[p].z, off);
      o[p].w += __shfl_xor(o[p].w, off);
    }
  }
  if (g == 0) {
#pragma unroll
    for (int p = 0; p < 4; ++p) *(float4*)&wo[w][p * 64 + l * 4] = o[p];
    if (l == 0) wl[w] = lsum;
  }
  __syncthreads();
  const float od = wo[0][t] + wo[1][t] + wo[2][t] + wo[3][t];
  float* apo = att_part + (size_t)(b * 8 + ss) * 264;
  if (t == 0) apo[0] = wl[0] + wl[1] + wl[2] + wl[3];
  apo[4 + t] = od;
}

// ---------------------------------------------------------------------------
// K4a: combine split partials (plain sums) -> cand_att_vec; attention gate;
// build inp_cat[b][768] = [att_vec | x_cont | h_tm1].  grid 128, block 256.
// ---------------------------------------------------------------------------
__global__ __launch_bounds__(256) void k4a_gate(
    const float* __restrict__ att_part, const float* __restrict__ h_tm1,
    const float* __restrict__ x_cont, const float* __restrict__ Wg,
    const float* __restrict__ bg_, float* __restrict__ inp_cat) {
  const int b = blockIdx.x, t = threadIdx.x;
  const float* ap = att_part + (size_t)b * 8 * 264;
  float lg = 0.f, od = 0.f;
#pragma unroll
  for (int ss = 0; ss < 8; ++ss) {
    lg += ap[ss * 264];
    od += ap[ss * 264 + 4 + t];
  }
  const float cand = od / lg;
  const float hv = h_tm1[b * 256 + t];
  const float xc = x_cont[b * 256 + t];
  float v = cand * Wg[t] + hv * Wg[256 + t] + xc * Wg[512 + t];
  for (int off = 32; off; off >>= 1) v += __shfl_xor(v, off);
  __shared__ float rr[4];
  __shared__ float gsh;
  const int w_ = t >> 6, lane = t & 63;
  if (lane == 0) rr[w_] = v;
  __syncthreads();
  if (t == 0) {
    const float s = rr[0] + rr[1] + rr[2] + rr[3] + bg_[0];
    gsh = 1.f / (1.f + expf(-s));
  }
  __syncthreads();
  inp_cat[b * 768 + t] = cand * gsh;
  inp_cat[b * 768 + 256 + t] = xc;
  inp_cat[b * 768 + 512 + t] = hv;
}

// ---------------------------------------------------------------------------
// K4b: LSTM cell.  Block bj handles columns {j0, j0+1} x all 4 gates x 128 b,
// K = 768 ([att_vec,x_cont] via W_ih then h_tm1 via W_hh).  Fuses c/h update.
// grid 128, block 256.
// ---------------------------------------------------------------------------
__global__ __launch_bounds__(256) void k4b_lstm(
    const float* __restrict__ inp_cat, const float* __restrict__ Wih,
    const float* __restrict__ bih, const float* __restrict__ Whh,
    const float* __restrict__ bhh, const float* __restrict__ c_tm1,
    float* __restrict__ h_out, float* __restrict__ c_out) {
  const int j0 = blockIdx.x * 2;
  const int t = threadIdx.x;
  __shared__ float inp_s[128][132];
  __shared__ float w_s[8][132];
  const int b = t >> 1, half = t & 1;
  float acc[4] = {0.f, 0.f, 0.f, 0.f};
  for (int kc = 0; kc < 6; ++kc) {
    const int kbase = kc * 128;
    for (int q = t; q < 4096; q += 256) {     // 128 x 128 floats
      const int row = q >> 5, c4 = q & 31;
      *(float4*)&inp_s[row][c4 * 4] =
          *(const float4*)(inp_cat + (size_t)row * 768 + kbase + c4 * 4);
    }
    {                                          // 8 x 128 floats, one f4/thread
      const int row = t >> 5, c4 = t & 31;
      const int gate = row & 3;
      const int j = j0 + (row >> 2);
      const int og = gate * 256 + j;
      const int kg = kbase + c4 * 4;
      float4 v;
      if (kg < 512) v = *(const float4*)(Wih + (size_t)og * 512 + kg);
      else          v = *(const float4*)(Whh + (size_t)og * 256 + (kg - 512));
      *(float4*)&w_s[row][c4 * 4] = v;
    }
    __syncthreads();
    for (int k = 0; k < 128; k += 4) {
      const float4 iv = *(const float4*)&inp_s[b][k];
#pragma unroll
      for (int g = 0; g < 4; ++g) {
        const float4 wv = *(const float4*)&w_s[half * 4 + g][k];
        acc[g] += iv.x * wv.x + iv.y * wv.y + iv.z * wv.z + iv.w * wv.w;
      }
    }
    __syncthreads();
  }
  const int j = j0 + half;
  const float gi = acc[0] + bih[j] + bhh[j];
  const float gf = acc[1] + bih[256 + j] + bhh[256 + j];
  const float gg = acc[2] + bih[512 + j] + bhh[512 + j];
  const float go = acc[3] + bih[768 + j] + bhh[768 + j];
  const float ct = c_tm1[b * 256 + j];
  const float i_ = 1.f / (1.f + expf(-gi));
  const float f_ = 1.f / (1.f + expf(-gf));
  const float g_ = tanhf(gg);
  const float o_ = 1.f / (1.f + expf(-go));
  const float c = f_ * ct + i_ * g_;
  const float h = o_ * tanhf(c);
  h_out[b * 256 + j] = h;
  c_out[b * 256 + j] = c;
}

// ---------------------------------------------------------------------------
// K5: head hidden layers (post-relu).  grid 128 (batch), block 256
// (t<128 -> actor_hid, t>=128 -> critic_hid).
// ---------------------------------------------------------------------------
__global__ __launch_bounds__(256) void k5_hid(
    const float* __restrict__ h_in, const float* __restrict__ Wah,
    const float* __restrict__ bah, const float* __restrict__ Wch,
    const float* __restrict__ bch, float* __restrict__ hidA,
    float* __restrict__ hidC) {
  const int b = blockIdx.x, t = threadIdx.x;
  __shared__ float hs[256];
  hs[t] = h_in[b * 256 + t];
  __syncthreads();
  const float* W = (t < 128) ? (Wah + (size_t)t * 256) : (Wch + (size_t)(t - 128) * 256);
  float s = (t < 128) ? bah[t] : bch[t - 128];
  for (int k = 0; k < 256; k += 4) {
    const float4 w = *(const float4*)(W + k);
    s += hs[k] * w.x + hs[k + 1] * w.y + hs[k + 2] * w.z + hs[k + 3] * w.w;
  }
  s = fmaxf(s, 0.f);
  if (t < 128) hidA[b * 128 + t] = s;
  else         hidC[b * 128 + (t - 128)] = s;
}

// ---------------------------------------------------------------------------
// K6: action logits GEMM [128,10000] = hidA[128,128] @ W_actor^T + b.
// grid (158, 4): batch split 4x; (157,0) computes value.  XOR-swizzled LDS.
// ---------------------------------------------------------------------------
__global__ __launch_bounds__(256) void k6_heads(
    const float* __restrict__ hidA, const float* __restrict__ hidC,
    const float* __restrict__ Wa, const float* __restrict__ ba,
    const float* __restrict__ Wc, const float* __restrict__ bc,
    float* __restrict__ logits, float* __restrict__ value) {
  const int t = threadIdx.x;
  const int bx = blockIdx.x, by = blockIdx.y;
  if (bx == 157) {
    if (by == 0 && t < 128) {
      const float* hc = hidC + (size_t)t * 128;
      float s = bc[0];
      for (int k = 0; k < 128; k += 4) {
        const float4 w = *(const float4*)(Wc + k);
        s += hc[k] * w.x + hc[k + 1] * w.y + hc[k + 2] * w.z + hc[k + 3] * w.w;
      }
      value[t] = s;
    }
    return;
  }
  const int o0 = bx * 64;
  const int b0 = by * 32;
  __shared__ float4 ha[32][32];
  __shared__ float4 wa[64][32];
  for (int q = t; q < 1024; q += 256) {    // 32 rows x 32 f4
    const int row = q >> 5, c4 = q & 31;
    ha[row][c4 ^ ((row >> 2) & 7)] =
        *(const float4*)(hidA + (size_t)(b0 + row) * 128 + c4 * 4);
  }
  for (int q = t; q < 2048; q += 256) {    // 64 rows x 32 f4
    const int row = q >> 5, c4 = q & 31;
    const int o = o0 + row;
    float4 v = make_float4(0.f, 0.f, 0.f, 0.f);
    if (o < WN) v = *(const float4*)(Wa + (size_t)o * 128 + c4 * 4);
    wa[row][c4 ^ ((row >> 2) & 7)] = v;
  }
  __syncthreads();
  const int og = t & 15, bq = t >> 4;      // 16 out-groups x 16 batch-groups
  float acc[2][4];
#pragma unroll
  for (int r = 0; r < 2; ++r)
#pragma unroll
    for (int i = 0; i < 4; ++i) acc[r][i] = 0.f;
#pragma unroll 4
  for (int c4 = 0; c4 < 32; ++c4) {
    float4 wv[4];
#pragma unroll
    for (int i = 0; i < 4; ++i) wv[i] = wa[og * 4 + i][c4 ^ (og & 7)];
#pragma unroll
    for (int r = 0; r < 2; ++r) {
      const int row = bq * 2 + r;
      const float4 hv = ha[row][c4 ^ ((row >> 2) & 7)];
#pragma unroll
      for (int i = 0; i < 4; ++i)
        acc[r][i] += hv.x * wv[i].x + hv.y * wv[i].y + hv.z * wv[i].z + hv.w * wv[i].w;
    }
  }
  const int obase = o0 + og * 4;
#pragma unroll
  for (int r = 0; r < 2; ++r) {
    const int bb = b0 + bq * 2 + r;
    if (obase + 3 < WN) {
      const float4 bias = *(const float4*)(ba + obase);
      float4 res;
      res.x = acc[r][0] + bias.x;
      res.y = acc[r][1] + bias.y;
      res.z = acc[r][2] + bias.z;
      res.w = acc[r][3] + bias.w;
      *(float4*)(logits + (size_t)bb * WN + obase) = res;
    } else {
      for (int i = 0; i < 4; ++i)
        if (obase + i < WN) logits[(size_t)bb * WN + obase + i] = acc[r][i] + ba[obase + i];
    }
  }
}

// ---------------------------------------------------------------------------
extern "C" void kernel_launch(void* const* d_in, const int* in_sizes, int n_in,
                              void* d_out, int out_size, void* d_ws, size_t ws_size,
                              hipStream_t stream) {
  const float* x     = (const float*)d_in[0];
  const float* feat  = (const float*)d_in[1];
  const float* h_tm1 = (const float*)d_in[2];
  const float* c_tm1 = (const float*)d_in[3];
  const float* Wx2c  = (const float*)d_in[4];
  const float* bx2c  = (const float*)d_in[5];
  const float* Wh2c  = (const float*)d_in[6];
  const float* bh2c  = (const float*)d_in[7];
  const float* Wc2k  = (const float*)d_in[8];
  const float* bc2k  = (const float*)d_in[9];
  const float* Wc2s  = (const float*)d_in[10];
  const float* bc2s  = (const float*)d_in[11];
  const float* Wag   = (const float*)d_in[12];
  const float* bag   = (const float*)d_in[13];
  const float* Wih   = (const float*)d_in[14];
  const float* bih   = (const float*)d_in[15];
  const float* Whh   = (const float*)d_in[16];
  const float* bhh   = (const float*)d_in[17];
  const float* Wah   = (const float*)d_in[18];
  const float* bah   = (const float*)d_in[19];
  const float* Wch   = (const float*)d_in[20];
  const float* bch   = (const float*)d_in[21];
  const float* Wa    = (const float*)d_in[22];
  const float* ba    = (const float*)d_in[23];
  const float* Wc    = (const float*)d_in[24];
  const float* bc    = (const float*)d_in[25];

  float* out    = (float*)d_out;
  float* logits = out;                 // 1,280,000
  float* value  = out + 1280000;       // 128
  float* h_out  = out + 1280128;       // 32,768
  float* c_out  = out + 1312896;       // 32,768

  float* wsf      = (float*)d_ws;
  float* part     = wsf;               // 40*32768 = 1,310,720
  float* x_cont   = part + 1310720;    // 32,768
  float* key_v    = x_cont + 32768;    // 32,768
  float* strength = key_v + 32768;     // 128
  float* key_n    = strength + 128;    // 128
  float* att_part = key_n + 128;       // 128*8*264 = 270,336
  float* inp_cat  = att_part + 270336; // 128*768 = 98,304
  float* hidA     = inp_cat + 98304;   // 16,384
  float* hidC     = hidA + 16384;      // 16,384

  k1_xcont<<<dim3(16, 40), 256, 0, stream>>>(x, Wx2c, part);
  k2_controller<<<128, 256, 0, stream>>>(part, bx2c, h_tm1, Wh2c, bh2c,
                                         Wc2k, bc2k, Wc2s, bc2s,
                                         x_cont, key_v, strength, key_n);
  k3_attn<<<dim3(8, 128), 256, 0, stream>>>(feat, key_v, strength, key_n, att_part);
  k4a_gate<<<128, 256, 0, stream>>>(att_part, h_tm1, x_cont, Wag, bag, inp_cat);
  k4b_lstm<<<128, 256, 0, stream>>>(inp_cat, Wih, bih, Whh, bhh, c_tm1, h_out, c_out);
  k5_hid<<<128, 256, 0, stream>>>(h_out, Wah, bah, Wch, bch, hidA, hidC);
  k6_heads<<<dim3(158, 4), 256, 0, stream>>>(hidA, hidC, Wa, ba, Wc, bc, logits, value);
}